// Round 5
// baseline (472.804 us; speedup 1.0000x reference)
//
#include <hip/hip_runtime.h>
#include <math.h>

#define B_C   4096   // comments
#define N_SRT 8192   // srt rows
#define D_C   768
#define D_S   1024
#define KSEL  2
#define NGRP  (N_SRT / 4)   // 2048 groups of 4 consecutive srt rows
#define PGRP  8             // groups refined per comment row (32 candidates)

typedef float  f32x4  __attribute__((ext_vector_type(4)));
typedef short  short8 __attribute__((ext_vector_type(8)));

__device__ inline unsigned short f2bf(float f) {           // RTNE float->bf16
    unsigned u = __float_as_uint(f);
    u += 0x7FFF + ((u >> 16) & 1);
    return (unsigned short)(u >> 16);
}
__device__ inline float bf2f(unsigned short h) {
    return __uint_as_float(((unsigned)h) << 16);
}

#define GLOAD_LDS16(gsrc, ldst)                                                     \
    __builtin_amdgcn_global_load_lds(                                               \
        (const __attribute__((address_space(1))) void*)(gsrc),                      \
        (__attribute__((address_space(3))) void*)(ldst), 16, 0, 0)

// ---------------------------------------------------------------------------
// Kernel 1 (fused, both transforms): C = relu(A @ W + bias) fp32 + bf16 copy.
// 128x128 block, 256 threads, 8x8 micro-tile, BK=16, double-buffered LDS
// (one __syncthreads per iter; its implicit vmcnt(0) drains global_load_lds).
//
// A tile XOR-swizzled (round-4 fix, conflict-free broadcast reads).
// B tile k-pair interleaved (round-5 fix): slot s of 1024B super-row h holds
//   k = 2h + ((s>>4)&1), 4-float col-block j = 2(s&15) + (s>>5).
// Read for (k, tx): addr = h*1024 + (tx + 16(k&1))*16 and +512 -> 16 lanes at
// 64B stride span all 8 bank-quads = 2-way aliasing = free (was 4-way).
// Both-sides rule: LDS dest linear tid*16; global source pre-permuted.
// ---------------------------------------------------------------------------
#define NB0 ((B_C / 128) * (D_S / 128))     // 256
#define NB1 ((N_SRT / 128) * (D_S / 128))   // 512

__global__ __launch_bounds__(256)
void transform_fused(const float* __restrict__ A0, const float* __restrict__ W0,
                     const float* __restrict__ b0, float* __restrict__ C0,
                     unsigned short* __restrict__ H0,
                     const float* __restrict__ A1, const float* __restrict__ W1,
                     const float* __restrict__ b1, float* __restrict__ C1,
                     unsigned short* __restrict__ H1) {
    __shared__ __align__(16) float As[2][128][16];   // 8KB each, A-swizzled
    __shared__ __align__(16) float Bs[2][2048];      // 8KB each, k-pair interleaved

    const bool p1 = (int)blockIdx.x >= NB0;
    const int  b  = p1 ? (int)blockIdx.x - NB0 : (int)blockIdx.x;
    const float* __restrict__ A = p1 ? A1 : A0;
    const float* __restrict__ W = p1 ? W1 : W0;
    const float* __restrict__ bias = p1 ? b1 : b0;
    float* __restrict__ C = p1 ? C1 : C0;
    unsigned short* __restrict__ H = p1 ? H1 : H0;
    const int K = p1 ? D_S : D_C;

    const int bn = (b & 7) * 128;         // N/128 == 8 for both problems
    const int bm = (b >> 3) * 128;

    const int tid = threadIdx.x;
    const int tx = tid & 15, ty = tid >> 4;

    // staging source offsets (2 chunks of 256 threads each)
    // A: idx -> row r=idx>>2, quad q=idx&3, pre-swizzled source block q^((r>>3)&3)
    // B: idx -> super-row h=idx>>6, slot s=idx&63:
    //      k = 2h + ((s>>4)&1), colblock = 2(s&15) + (s>>5)
    int a_off[2], w_off[2];
#pragma unroll
    for (int i = 0; i < 2; ++i) {
        const int idx = tid + i * 256;
        const int r = idx >> 2, q = idx & 3;
        a_off[i] = r * K + (q ^ ((r >> 3) & 3)) * 4;   // + bm*K + k0
        const int s = idx & 63;
        const int kloc = 2 * (idx >> 6) + ((s >> 4) & 1);
        const int cb   = 2 * (s & 15) + (s >> 5);
        w_off[i] = kloc * D_S + cb * 4;                // + k0*D_S + bn
    }

#define STAGE(bufi, k0)                                                        \
    {                                                                          \
        _Pragma("unroll")                                                      \
        for (int i = 0; i < 2; ++i) {                                          \
            const int idx = tid + i * 256;                                     \
            GLOAD_LDS16(A + (size_t)bm * K + (k0) + a_off[i],                  \
                        (char*)&As[bufi][0][0] + idx * 16);                    \
            GLOAD_LDS16(W + (size_t)(k0) * D_S + bn + w_off[i],                \
                        (char*)&Bs[bufi][0] + idx * 16);                       \
        }                                                                      \
    }

    float acc[8][8] = {};

    STAGE(0, 0);
    __syncthreads();                       // drains vmcnt(0) + barrier

    const int nk = K / 16;
    for (int t = 0; t < nk; ++t) {
        const int cur = t & 1;
        if (t + 1 < nk) STAGE(t & 1 ? 0 : 1, (t + 1) * 16);

        const float* __restrict__ Bf = &Bs[cur][0];
#pragma unroll
        for (int kq = 0; kq < 4; ++kq) {
            f32x4 a4[8];
#pragma unroll
            for (int i = 0; i < 8; ++i)
                a4[i] = *reinterpret_cast<const f32x4*>(
                    &As[cur][ty * 8 + i][(kq ^ (ty & 3)) * 4]);   // read-side swizzle
#pragma unroll
            for (int k2 = 0; k2 < 4; ++k2) {
                const int k = kq * 4 + k2;
                const int boff = (k >> 1) * 256 + (tx + ((k & 1) << 4)) * 4;
                const f32x4 bx = *reinterpret_cast<const f32x4*>(Bf + boff);
                const f32x4 by = *reinterpret_cast<const f32x4*>(Bf + boff + 128);
                const float bv[8] = {bx[0], bx[1], bx[2], bx[3], by[0], by[1], by[2], by[3]};
#pragma unroll
                for (int i = 0; i < 8; ++i) {
                    const float av = a4[i][k2];
#pragma unroll
                    for (int j = 0; j < 8; ++j)
                        acc[i][j] = fmaf(av, bv[j], acc[i][j]);
                }
            }
        }
        __syncthreads();   // waves done reading buf[cur]; next stage's loads drained
    }
#undef STAGE

    // epilogue: bias + relu, fp32 store + bf16 store
    const f32x4 g0 = *reinterpret_cast<const f32x4*>(&bias[bn + tx * 8]);
    const f32x4 g1 = *reinterpret_cast<const f32x4*>(&bias[bn + tx * 8 + 4]);
#pragma unroll
    for (int i = 0; i < 8; ++i) {
        const int m = bm + ty * 8 + i;
        const int n = bn + tx * 8;
        f32x4 o0, o1;
#pragma unroll
        for (int j = 0; j < 4; ++j) {
            o0[j] = fmaxf(acc[i][j]     + g0[j], 0.f);
            o1[j] = fmaxf(acc[i][j + 4] + g1[j], 0.f);
        }
        *reinterpret_cast<f32x4*>(&C[(size_t)m * D_S + n])     = o0;
        *reinterpret_cast<f32x4*>(&C[(size_t)m * D_S + n + 4]) = o1;
        short8 h;
#pragma unroll
        for (int j = 0; j < 4; ++j) {
            h[j]     = (short)f2bf(o0[j]);
            h[j + 4] = (short)f2bf(o1[j]);
        }
        *reinterpret_cast<short8*>(&H[(size_t)m * D_S + n]) = h;
    }
}

// ---------------------------------------------------------------------------
// Kernel 2: bf16 MFMA score filter. Block = 128 srt x 128 comments, 4 waves
// (2x2), each wave a 64x64 tile (4x4 frags of 16x16x32 MFMA). BK=64, LDS
// XOR-swizzled via pre-swizzled global_load_lds sources (both-sides rule).
// Round 5: stage-ahead double-buffer, one barrier/iter — STAGE(t+1) issued
// before compute(t), so load latency hides under 32 MFMAs instead of being
// drained back-to-back at the next barrier.
// Emits per-(comment, 4-wide-n-group) max into G[B_C][NGRP] (bf16).
// ---------------------------------------------------------------------------
__global__ __launch_bounds__(256)
void scores_filter(const unsigned short* __restrict__ TSh,  // [N_SRT][D_S] bf16
                   const unsigned short* __restrict__ TCh,  // [B_C][D_S] bf16
                   unsigned short* __restrict__ G) {        // [B_C][NGRP] bf16
    __shared__ __align__(16) unsigned short sA[2][128 * 64];   // TS chunk, swizzled
    __shared__ __align__(16) unsigned short sB[2][128 * 64];   // TC chunk, swizzled
    const int tid  = threadIdx.x;
    const int lane = tid & 63;
    const int w    = tid >> 6;
    const int lr   = lane & 15, lg = lane >> 4;
    const int wn   = w & 1, wc = w >> 1;
    const int n0   = blockIdx.x * 128;
    const int c0   = blockIdx.y * 128;

    const f32x4 vzero = {0.f, 0.f, 0.f, 0.f};
    f32x4 acc[4][4];
#pragma unroll
    for (int i = 0; i < 4; ++i)
#pragma unroll
        for (int j = 0; j < 4; ++j) acc[i][j] = vzero;

    const int sr = tid >> 3;  // staging row within 32-row stripe
    const int sb = tid & 7;   // 16B block within 128B row

#define FSTAGE(bufi, kb)                                                       \
    {                                                                          \
        _Pragma("unroll")                                                      \
        for (int i = 0; i < 4; ++i) {                                          \
            const int r  = i * 32 + sr;                                        \
            const int sw = (sb ^ (r & 7)) * 8;                                 \
            GLOAD_LDS16(TSh + (size_t)(n0 + r) * D_S + (kb) + sw,              \
                        (char*)&sA[bufi][0] + i * 4096 + tid * 16);            \
            GLOAD_LDS16(TCh + (size_t)(c0 + r) * D_S + (kb) + sw,              \
                        (char*)&sB[bufi][0] + i * 4096 + tid * 16);            \
        }                                                                      \
    }

    FSTAGE(0, 0);
    __syncthreads();

    for (int kc = 0; kc < 16; ++kc) {
        const int cur = kc & 1;
        if (kc + 1 < 16) FSTAGE(cur ^ 1, (kc + 1) * 64);

#pragma unroll
        for (int kt = 0; kt < 2; ++kt) {
            short8 a[4], b[4];
#pragma unroll
            for (int t = 0; t < 4; ++t) {
                const int ra = wn * 64 + t * 16 + lr;
                a[t] = *(const short8*)((const char*)&sA[cur][0] + ra * 128 +
                                        (((kt * 4 + lg) ^ (ra & 7)) * 16));
                const int rb = wc * 64 + t * 16 + lr;
                b[t] = *(const short8*)((const char*)&sB[cur][0] + rb * 128 +
                                        (((kt * 4 + lg) ^ (rb & 7)) * 16));
            }
#pragma unroll
            for (int i = 0; i < 4; ++i)
#pragma unroll
                for (int j = 0; j < 4; ++j)
                    acc[i][j] = __builtin_amdgcn_mfma_f32_16x16x32_bf16(
                        a[i], b[j], acc[i][j], 0, 0, 0);
        }
        __syncthreads();
    }
#undef FSTAGE

    // extraction: per-lane j-run is 4 consecutive n => natural 4-wide group max
#pragma unroll
    for (int nt = 0; nt < 4; ++nt) {
        const int n4 = (n0 >> 2) + wn * 16 + nt * 4 + lg;
#pragma unroll
        for (int ct = 0; ct < 4; ++ct) {
            const int c = c0 + wc * 64 + ct * 16 + lr;
            const f32x4 v = acc[nt][ct];
            const float m = fmaxf(fmaxf(v.x, v.y), fmaxf(v.z, v.w));
            G[(size_t)c * NGRP + n4] = f2bf(m);
        }
    }
}

// ---------------------------------------------------------------------------
// Kernel 3: per comment row, top-8 groups by approx group-max (one wave/row).
// ---------------------------------------------------------------------------
__global__ __launch_bounds__(256)
void top_groups(const unsigned short* __restrict__ G, int* __restrict__ g8) {
    const int w = threadIdx.x >> 6, lane = threadIdx.x & 63;
    const int row = blockIdx.x * 4 + w;
    float v[32];
    const unsigned short* gp = G + (size_t)row * NGRP + lane * 32;
#pragma unroll
    for (int i = 0; i < 4; ++i) {
        short8 h = *(const short8*)(gp + i * 8);
#pragma unroll
        for (int j = 0; j < 8; ++j) v[i * 8 + j] = bf2f((unsigned short)h[j]);
    }
    float pv = INFINITY; int pi = -1;   // previous winner in total order
    int gl[8];
#pragma unroll
    for (int k = 0; k < 8; ++k) {
        float bv = -INFINITY; int bi = NGRP;
#pragma unroll
        for (int i = 0; i < 32; ++i) {
            const int idx = lane * 32 + i;
            const bool after  = (v[i] < pv) || (v[i] == pv && idx > pi);
            const bool before = (v[i] > bv) || (v[i] == bv && idx < bi);
            if (after && before) { bv = v[i]; bi = idx; }
        }
#pragma unroll
        for (int off = 32; off >= 1; off >>= 1) {
            const float ov = __shfl_xor(bv, off);
            const int   oi = __shfl_xor(bi, off);
            if ((ov > bv) || (ov == bv && oi < bi)) { bv = ov; bi = oi; }
        }
        gl[k] = bi; pv = bv; pi = bi;
    }
#pragma unroll
    for (int a = 0; a < 8; ++a)
#pragma unroll
        for (int b2 = 0; b2 < 7; ++b2)
            if (gl[b2] > gl[b2 + 1]) { int t = gl[b2]; gl[b2] = gl[b2 + 1]; gl[b2 + 1] = t; }
    if (lane == 0) {
        int4 lo = make_int4(gl[0], gl[1], gl[2], gl[3]);
        int4 hi = make_int4(gl[4], gl[5], gl[6], gl[7]);
        *reinterpret_cast<int4*>(g8 + (size_t)row * 8)     = lo;
        *reinterpret_cast<int4*>(g8 + (size_t)row * 8 + 4) = hi;
    }
}

// ---------------------------------------------------------------------------
// Kernel 4: exact fp32 refine of the 32 candidates per row -> top-2 indices.
// ---------------------------------------------------------------------------
__global__ __launch_bounds__(256)
void refine(const float* __restrict__ t_c, const float* __restrict__ t_s,
            const int* __restrict__ g8, int* __restrict__ tidx) {
    __shared__ float tc[D_S];
    __shared__ float sc[4 * PGRP];
    const int row = blockIdx.x;
    const int tid = threadIdx.x;
    *reinterpret_cast<float4*>(&tc[tid * 4]) =
        *reinterpret_cast<const float4*>(&t_c[(size_t)row * D_S + tid * 4]);
    __syncthreads();
    const int w = tid >> 6, lane = tid & 63;
    float4 c4[4];
#pragma unroll
    for (int q = 0; q < 4; ++q)
        c4[q] = *reinterpret_cast<const float4*>(&tc[lane * 16 + q * 4]);
#pragma unroll
    for (int i = 0; i < 2; ++i) {
        const int slotg = w * 2 + i;
        const int g = g8[(size_t)row * 8 + slotg];
#pragma unroll
        for (int o = 0; o < 4; ++o) {
            const int n = g * 4 + o;
            const float* ts = t_s + (size_t)n * D_S + lane * 16;
            float p = 0.f;
#pragma unroll
            for (int q = 0; q < 4; ++q) {
                const float4 tv = *reinterpret_cast<const float4*>(ts + q * 4);
                p += c4[q].x * tv.x + c4[q].y * tv.y + c4[q].z * tv.z + c4[q].w * tv.w;
            }
#pragma unroll
            for (int off = 32; off >= 1; off >>= 1) p += __shfl_xor(p, off);
            if (lane == 0) sc[slotg * 4 + o] = p;
        }
    }
    __syncthreads();
    if (tid == 0) {
        float v1 = -INFINITY, v2 = -INFINITY; int i1 = 0, i2 = 0;
#pragma unroll
        for (int s = 0; s < 4 * PGRP; ++s) {
            const int n = g8[(size_t)row * 8 + (s >> 2)] * 4 + (s & 3);
            const float v = sc[s];
            if (v > v1)      { v2 = v1; i2 = i1; v1 = v; i1 = n; }
            else if (v > v2) { v2 = v; i2 = n; }
        }
        tidx[row * 2 + 0] = i1;
        tidx[row * 2 + 1] = i2;
    }
}

// ---------------------------------------------------------------------------
// Kernel 5: gather selected transformed-srt rows -> output [B_C, 2, D_S].
// ---------------------------------------------------------------------------
__global__ __launch_bounds__(256)
void gather_rows(const float* __restrict__ TS, const int* __restrict__ topIdx,
                 float* __restrict__ out) {
    const int row = blockIdx.x;
    const int src = topIdx[row];
    const int tid = threadIdx.x;
    const float4 v = *reinterpret_cast<const float4*>(&TS[(size_t)src * D_S + tid * 4]);
    *reinterpret_cast<float4*>(&out[(size_t)row * D_S + tid * 4]) = v;
}

// ---------------------------------------------------------------------------
extern "C" void kernel_launch(void* const* d_in, const int* in_sizes, int n_in,
                              void* d_out, int out_size, void* d_ws, size_t ws_size,
                              hipStream_t stream) {
    const float* srt      = (const float*)d_in[0];  // [8192,1024]
    const float* comments = (const float*)d_in[1];  // [4096,768]
    const float* Wc       = (const float*)d_in[2];  // [768,1024]
    const float* bc       = (const float*)d_in[3];  // [1024]
    const float* Ws       = (const float*)d_in[4];  // [1024,1024]
    const float* bs       = (const float*)d_in[5];  // [1024]
    float* out = (float*)d_out;

    // workspace layout (~88.2 MB)
    char* p = (char*)d_ws;
    float* t_c = (float*)p;          p += (size_t)B_C * D_S * 4;     // 16 MB
    float* t_s = (float*)p;          p += (size_t)N_SRT * D_S * 4;   // 32 MB
    unsigned short* tc_h = (unsigned short*)p; p += (size_t)B_C * D_S * 2;    // 8 MB
    unsigned short* ts_h = (unsigned short*)p; p += (size_t)N_SRT * D_S * 2;  // 16 MB
    unsigned short* G    = (unsigned short*)p; p += (size_t)B_C * NGRP * 2;   // 16 MB
    int* g8   = (int*)p;             p += (size_t)B_C * PGRP * 4;    // 128 KB
    int* tidx = (int*)p;

    // fused fp32 transforms (exact — index selection depends on these)
    transform_fused<<<NB0 + NB1, 256, 0, stream>>>(
        comments, Wc, bc, t_c, tc_h,
        srt,      Ws, bs, t_s, ts_h);

    scores_filter<<<dim3(N_SRT / 128, B_C / 128), 256, 0, stream>>>(ts_h, tc_h, G);
    top_groups<<<B_C / 4, 256, 0, stream>>>(G, g8);
    refine<<<B_C, 256, 0, stream>>>(t_c, t_s, g8, tidx);
    gather_rows<<<B_C * KSEL, 256, 0, stream>>>(t_s, tidx, out);
}

// Round 6
// 411.284 us; speedup vs baseline: 1.1496x; 1.1496x over previous
//
#include <hip/hip_runtime.h>
#include <math.h>

#define B_C   4096   // comments
#define N_SRT 8192   // srt rows
#define D_C   768
#define D_S   1024
#define KSEL  2
#define NGRP  (N_SRT / 4)   // 2048 groups of 4 consecutive srt rows
#define PGRP  8             // groups refined per comment row (32 candidates)

typedef float  f32x4  __attribute__((ext_vector_type(4)));
typedef short  short8 __attribute__((ext_vector_type(8)));

__device__ inline unsigned short f2bf(float f) {           // RTNE float->bf16
    unsigned u = __float_as_uint(f);
    u += 0x7FFF + ((u >> 16) & 1);
    return (unsigned short)(u >> 16);
}
__device__ inline float bf2f(unsigned short h) {
    return __uint_as_float(((unsigned)h) << 16);
}
// 3-term bf16 split: x = h + m + l + eps, |eps| <= 2^-24 |x|
__device__ inline void split3(float x, unsigned short& h, unsigned short& m,
                              unsigned short& l) {
    h = f2bf(x); const float r1 = x - bf2f(h);    // exact
    m = f2bf(r1); const float r2 = r1 - bf2f(m);  // exact
    l = f2bf(r2);
}

#define GLOAD_LDS16(gsrc, ldst)                                                     \
    __builtin_amdgcn_global_load_lds(                                               \
        (const __attribute__((address_space(1))) void*)(gsrc),                      \
        (__attribute__((address_space(3))) void*)(ldst), 16, 0, 0)

// ---------------------------------------------------------------------------
// split_act: elementwise 3-plane bf16 split of activations (srt + comments).
// Planes stored [3][M][K] contiguous per matrix.
// ---------------------------------------------------------------------------
__global__ __launch_bounds__(256)
void split_act(const float* __restrict__ srt, const float* __restrict__ com,
               unsigned short* __restrict__ pS, unsigned short* __restrict__ pC) {
    const int g = blockIdx.x * 256 + threadIdx.x;   // one 8-elem group / thread
    const int E0 = N_SRT * D_S / 8;                 // 1048576 srt groups
    const float* src;
    unsigned short* dst;
    size_t stride;
    if (g < E0) {
        src = srt + (size_t)g * 8; dst = pS + (size_t)g * 8;
        stride = (size_t)N_SRT * D_S;
    } else {
        const int g2 = g - E0;
        src = com + (size_t)g2 * 8; dst = pC + (size_t)g2 * 8;
        stride = (size_t)B_C * D_C;
    }
    const float4 a = *reinterpret_cast<const float4*>(src);
    const float4 b = *reinterpret_cast<const float4*>(src + 4);
    const float x[8] = {a.x, a.y, a.z, a.w, b.x, b.y, b.z, b.w};
    short8 hv, mv, lv;
#pragma unroll
    for (int j = 0; j < 8; ++j) {
        unsigned short h, m, l;
        split3(x[j], h, m, l);
        hv[j] = (short)h; mv[j] = (short)m; lv[j] = (short)l;
    }
    *reinterpret_cast<short8*>(dst)              = hv;
    *reinterpret_cast<short8*>(dst + stride)     = mv;
    *reinterpret_cast<short8*>(dst + 2 * stride) = lv;
}

// ---------------------------------------------------------------------------
// split_w: W[k][n] (row-stride 1024) -> 3 bf16 planes of W^T: Wt[p][n][k].
// 64x64 LDS transpose tile, conflict-free (pad 65).
// ---------------------------------------------------------------------------
__global__ __launch_bounds__(256)
void split_w(const float* __restrict__ W, unsigned short* __restrict__ Wt, int K) {
    __shared__ float t[64][65];
    const int n0 = blockIdx.x * 64, k0 = blockIdx.y * 64;
    const int tid = threadIdx.x;
    const int c = tid & 63, rq = tid >> 6;
#pragma unroll
    for (int j = 0; j < 16; ++j) {
        const int kr = rq * 16 + j;
        t[kr][c] = W[(size_t)(k0 + kr) * D_S + n0 + c];
    }
    __syncthreads();
    const size_t PS = (size_t)K * D_S;    // plane stride (elems)
#pragma unroll
    for (int j = 0; j < 16; ++j) {
        const int nr = rq * 16 + j;
        const float v = t[c][nr];          // W[k0+c][n0+nr]
        unsigned short h, m, l;
        split3(v, h, m, l);
        const size_t o = (size_t)(n0 + nr) * K + k0 + c;
        Wt[o] = h; Wt[o + PS] = m; Wt[o + 2 * PS] = l;
    }
}

// ---------------------------------------------------------------------------
// transform_mfma<K>: C = relu(Act @ W + bias) via bf16x6 emulated fp32.
// One MFMA chain over expanded K' = 6K; plane-pair pp in {hh,hm,mh,mm,hl,lh}.
// Structure cloned from scores_filter (verified): 128x128 tile, 4 waves 2x2,
// BK=64, XOR-swizzled pre-swizzled global_load_lds staging, stage-ahead dbuf.
// Operand roles: A = Wt rows (out cols n), B = Act rows (m) -> lane holds
// f32x4 over 4 consecutive n for fixed m => vectorized C stores.
// ---------------------------------------------------------------------------
template<int K>
__global__ __launch_bounds__(256)
void transform_mfma(const unsigned short* __restrict__ actP,  // [3][M][K]
                    const unsigned short* __restrict__ wtP,   // [3][1024][K]
                    const float* __restrict__ bias,
                    float* __restrict__ C,                    // [M][1024]
                    unsigned short* __restrict__ H,           // [M][1024] bf16
                    size_t aps) {                             // act plane stride
    __shared__ __align__(16) unsigned short sA[2][128 * 64];  // Wt tile
    __shared__ __align__(16) unsigned short sB[2][128 * 64];  // Act tile
    const int tid  = threadIdx.x;
    const int lane = tid & 63;
    const int w    = tid >> 6;
    const int lr   = lane & 15, lg = lane >> 4;
    const int wn   = w & 1, wc = w >> 1;
    const int bn   = blockIdx.x * 128;    // out-col tile (1024/128 = 8)
    const int bm   = blockIdx.y * 128;    // act-row tile

    const size_t wps = (size_t)D_S * K;   // wt plane stride

    const f32x4 vzero = {0.f, 0.f, 0.f, 0.f};
    f32x4 acc[4][4];
#pragma unroll
    for (int i = 0; i < 4; ++i)
#pragma unroll
        for (int j = 0; j < 4; ++j) acc[i][j] = vzero;

    const int sr = tid >> 3;  // staging row within 32-row stripe
    const int sb = tid & 7;   // 16B block within 128B row

    constexpr int KC = K / 64;       // chunks per plane-pair
    constexpr int NT = 6 * KC;

    auto stage = [&](int buf, int t) {
        const int pp = t / KC;                 // const divisor
        const int kb = (t - pp * KC) * 64;
        int pA, pB;                            // wt plane, act plane
        switch (pp) {
            case 0: pA = 0; pB = 0; break;
            case 1: pA = 0; pB = 1; break;
            case 2: pA = 1; pB = 0; break;
            case 3: pA = 1; pB = 1; break;
            case 4: pA = 0; pB = 2; break;
            default: pA = 2; pB = 0; break;
        }
        const unsigned short* gA = wtP + (size_t)pA * wps + (size_t)bn * K + kb;
        const unsigned short* gB = actP + (size_t)pB * aps + (size_t)bm * K + kb;
#pragma unroll
        for (int i = 0; i < 4; ++i) {
            const int r  = i * 32 + sr;
            const int sw = (sb ^ (r & 7)) * 8;     // inverse-swizzled k offset
            GLOAD_LDS16(gA + (size_t)r * K + sw,
                        (char*)&sA[buf][0] + i * 4096 + tid * 16);
            GLOAD_LDS16(gB + (size_t)r * K + sw,
                        (char*)&sB[buf][0] + i * 4096 + tid * 16);
        }
    };

    stage(0, 0);
    __syncthreads();

    for (int t = 0; t < NT; ++t) {
        const int cur = t & 1;
        if (t + 1 < NT) stage(cur ^ 1, t + 1);

#pragma unroll
        for (int kt = 0; kt < 2; ++kt) {
            short8 a[4], b[4];
#pragma unroll
            for (int t4 = 0; t4 < 4; ++t4) {
                const int ra = wn * 64 + t4 * 16 + lr;
                a[t4] = *(const short8*)((const char*)&sA[cur][0] + ra * 128 +
                                         (((kt * 4 + lg) ^ (ra & 7)) * 16));
                const int rb = wc * 64 + t4 * 16 + lr;
                b[t4] = *(const short8*)((const char*)&sB[cur][0] + rb * 128 +
                                         (((kt * 4 + lg) ^ (rb & 7)) * 16));
            }
#pragma unroll
            for (int i = 0; i < 4; ++i)
#pragma unroll
                for (int j = 0; j < 4; ++j)
                    acc[i][j] = __builtin_amdgcn_mfma_f32_16x16x32_bf16(
                        a[i], b[j], acc[i][j], 0, 0, 0);
        }
        __syncthreads();
    }

    // epilogue: n = bn + wn*64 + i*16 + lg*4 + reg;  m = bm + wc*64 + j*16 + lr
#pragma unroll
    for (int i = 0; i < 4; ++i) {
        const int n = bn + wn * 64 + i * 16 + lg * 4;
        const f32x4 bb = *reinterpret_cast<const f32x4*>(&bias[n]);
#pragma unroll
        for (int j = 0; j < 4; ++j) {
            const int m = bm + wc * 64 + j * 16 + lr;
            f32x4 o;
#pragma unroll
            for (int q = 0; q < 4; ++q)
                o[q] = fmaxf(acc[i][j][q] + bb[q], 0.f);
            *reinterpret_cast<f32x4*>(&C[(size_t)m * D_S + n]) = o;
            ushort4 hh;
            hh.x = f2bf(o[0]); hh.y = f2bf(o[1]);
            hh.z = f2bf(o[2]); hh.w = f2bf(o[3]);
            *reinterpret_cast<ushort4*>(&H[(size_t)m * D_S + n]) = hh;
        }
    }
}

// ---------------------------------------------------------------------------
// FALLBACK (round-5 verified): fused fp32 VALU transforms. Used when ws_size
// is too small for the bf16x6 plane workspace.
// ---------------------------------------------------------------------------
#define NB0 ((B_C / 128) * (D_S / 128))     // 256
#define NB1 ((N_SRT / 128) * (D_S / 128))   // 512

__global__ __launch_bounds__(256)
void transform_fused(const float* __restrict__ A0, const float* __restrict__ W0,
                     const float* __restrict__ b0, float* __restrict__ C0,
                     unsigned short* __restrict__ H0,
                     const float* __restrict__ A1, const float* __restrict__ W1,
                     const float* __restrict__ b1, float* __restrict__ C1,
                     unsigned short* __restrict__ H1) {
    __shared__ __align__(16) float As[2][128][16];
    __shared__ __align__(16) float Bs[2][2048];

    const bool p1 = (int)blockIdx.x >= NB0;
    const int  b  = p1 ? (int)blockIdx.x - NB0 : (int)blockIdx.x;
    const float* __restrict__ A = p1 ? A1 : A0;
    const float* __restrict__ W = p1 ? W1 : W0;
    const float* __restrict__ bias = p1 ? b1 : b0;
    float* __restrict__ C = p1 ? C1 : C0;
    unsigned short* __restrict__ H = p1 ? H1 : H0;
    const int K = p1 ? D_S : D_C;

    const int bn = (b & 7) * 128;
    const int bm = (b >> 3) * 128;

    const int tid = threadIdx.x;
    const int tx = tid & 15, ty = tid >> 4;

    int a_off[2], w_off[2];
#pragma unroll
    for (int i = 0; i < 2; ++i) {
        const int idx = tid + i * 256;
        const int r = idx >> 2, q = idx & 3;
        a_off[i] = r * K + (q ^ ((r >> 3) & 3)) * 4;
        const int s = idx & 63;
        const int kloc = 2 * (idx >> 6) + ((s >> 4) & 1);
        const int cb   = 2 * (s & 15) + (s >> 5);
        w_off[i] = kloc * D_S + cb * 4;
    }

#define STAGE(bufi, k0)                                                        \
    {                                                                          \
        _Pragma("unroll")                                                      \
        for (int i = 0; i < 2; ++i) {                                          \
            const int idx = tid + i * 256;                                     \
            GLOAD_LDS16(A + (size_t)bm * K + (k0) + a_off[i],                  \
                        (char*)&As[bufi][0][0] + idx * 16);                    \
            GLOAD_LDS16(W + (size_t)(k0) * D_S + bn + w_off[i],                \
                        (char*)&Bs[bufi][0] + idx * 16);                       \
        }                                                                      \
    }

    float acc[8][8] = {};

    STAGE(0, 0);
    __syncthreads();

    const int nk = K / 16;
    for (int t = 0; t < nk; ++t) {
        const int cur = t & 1;
        if (t + 1 < nk) STAGE(t & 1 ? 0 : 1, (t + 1) * 16);

        const float* __restrict__ Bf = &Bs[cur][0];
#pragma unroll
        for (int kq = 0; kq < 4; ++kq) {
            f32x4 a4[8];
#pragma unroll
            for (int i = 0; i < 8; ++i)
                a4[i] = *reinterpret_cast<const f32x4*>(
                    &As[cur][ty * 8 + i][(kq ^ (ty & 3)) * 4]);
#pragma unroll
            for (int k2 = 0; k2 < 4; ++k2) {
                const int k = kq * 4 + k2;
                const int boff = (k >> 1) * 256 + (tx + ((k & 1) << 4)) * 4;
                const f32x4 bx = *reinterpret_cast<const f32x4*>(Bf + boff);
                const f32x4 by = *reinterpret_cast<const f32x4*>(Bf + boff + 128);
                const float bv[8] = {bx[0], bx[1], bx[2], bx[3], by[0], by[1], by[2], by[3]};
#pragma unroll
                for (int i = 0; i < 8; ++i) {
                    const float av = a4[i][k2];
#pragma unroll
                    for (int j = 0; j < 8; ++j)
                        acc[i][j] = fmaf(av, bv[j], acc[i][j]);
                }
            }
        }
        __syncthreads();
    }
#undef STAGE

    const f32x4 g0 = *reinterpret_cast<const f32x4*>(&bias[bn + tx * 8]);
    const f32x4 g1 = *reinterpret_cast<const f32x4*>(&bias[bn + tx * 8 + 4]);
#pragma unroll
    for (int i = 0; i < 8; ++i) {
        const int m = bm + ty * 8 + i;
        const int n = bn + tx * 8;
        f32x4 o0, o1;
#pragma unroll
        for (int j = 0; j < 4; ++j) {
            o0[j] = fmaxf(acc[i][j]     + g0[j], 0.f);
            o1[j] = fmaxf(acc[i][j + 4] + g1[j], 0.f);
        }
        *reinterpret_cast<f32x4*>(&C[(size_t)m * D_S + n])     = o0;
        *reinterpret_cast<f32x4*>(&C[(size_t)m * D_S + n + 4]) = o1;
        short8 h;
#pragma unroll
        for (int j = 0; j < 4; ++j) {
            h[j]     = (short)f2bf(o0[j]);
            h[j + 4] = (short)f2bf(o1[j]);
        }
        *reinterpret_cast<short8*>(&H[(size_t)m * D_S + n]) = h;
    }
}

// ---------------------------------------------------------------------------
// Kernel 2: bf16 MFMA score filter (unchanged, verified).
// ---------------------------------------------------------------------------
__global__ __launch_bounds__(256)
void scores_filter(const unsigned short* __restrict__ TSh,
                   const unsigned short* __restrict__ TCh,
                   unsigned short* __restrict__ G) {
    __shared__ __align__(16) unsigned short sA[2][128 * 64];
    __shared__ __align__(16) unsigned short sB[2][128 * 64];
    const int tid  = threadIdx.x;
    const int lane = tid & 63;
    const int w    = tid >> 6;
    const int lr   = lane & 15, lg = lane >> 4;
    const int wn   = w & 1, wc = w >> 1;
    const int n0   = blockIdx.x * 128;
    const int c0   = blockIdx.y * 128;

    const f32x4 vzero = {0.f, 0.f, 0.f, 0.f};
    f32x4 acc[4][4];
#pragma unroll
    for (int i = 0; i < 4; ++i)
#pragma unroll
        for (int j = 0; j < 4; ++j) acc[i][j] = vzero;

    const int sr = tid >> 3;
    const int sb = tid & 7;

#define FSTAGE(bufi, kb)                                                       \
    {                                                                          \
        _Pragma("unroll")                                                      \
        for (int i = 0; i < 4; ++i) {                                          \
            const int r  = i * 32 + sr;                                        \
            const int sw = (sb ^ (r & 7)) * 8;                                 \
            GLOAD_LDS16(TSh + (size_t)(n0 + r) * D_S + (kb) + sw,              \
                        (char*)&sA[bufi][0] + i * 4096 + tid * 16);            \
            GLOAD_LDS16(TCh + (size_t)(c0 + r) * D_S + (kb) + sw,              \
                        (char*)&sB[bufi][0] + i * 4096 + tid * 16);            \
        }                                                                      \
    }

    FSTAGE(0, 0);
    __syncthreads();

    for (int kc = 0; kc < 16; ++kc) {
        const int cur = kc & 1;
        if (kc + 1 < 16) FSTAGE(cur ^ 1, (kc + 1) * 64);

#pragma unroll
        for (int kt = 0; kt < 2; ++kt) {
            short8 a[4], b[4];
#pragma unroll
            for (int t = 0; t < 4; ++t) {
                const int ra = wn * 64 + t * 16 + lr;
                a[t] = *(const short8*)((const char*)&sA[cur][0] + ra * 128 +
                                        (((kt * 4 + lg) ^ (ra & 7)) * 16));
                const int rb = wc * 64 + t * 16 + lr;
                b[t] = *(const short8*)((const char*)&sB[cur][0] + rb * 128 +
                                        (((kt * 4 + lg) ^ (rb & 7)) * 16));
            }
#pragma unroll
            for (int i = 0; i < 4; ++i)
#pragma unroll
                for (int j = 0; j < 4; ++j)
                    acc[i][j] = __builtin_amdgcn_mfma_f32_16x16x32_bf16(
                        a[i], b[j], acc[i][j], 0, 0, 0);
        }
        __syncthreads();
    }
#undef FSTAGE

#pragma unroll
    for (int nt = 0; nt < 4; ++nt) {
        const int n4 = (n0 >> 2) + wn * 16 + nt * 4 + lg;
#pragma unroll
        for (int ct = 0; ct < 4; ++ct) {
            const int c = c0 + wc * 64 + ct * 16 + lr;
            const f32x4 v = acc[nt][ct];
            const float m = fmaxf(fmaxf(v.x, v.y), fmaxf(v.z, v.w));
            G[(size_t)c * NGRP + n4] = f2bf(m);
        }
    }
}

// ---------------------------------------------------------------------------
// Kernel 3: per comment row, top-8 groups by approx group-max (unchanged).
// ---------------------------------------------------------------------------
__global__ __launch_bounds__(256)
void top_groups(const unsigned short* __restrict__ G, int* __restrict__ g8) {
    const int w = threadIdx.x >> 6, lane = threadIdx.x & 63;
    const int row = blockIdx.x * 4 + w;
    float v[32];
    const unsigned short* gp = G + (size_t)row * NGRP + lane * 32;
#pragma unroll
    for (int i = 0; i < 4; ++i) {
        short8 h = *(const short8*)(gp + i * 8);
#pragma unroll
        for (int j = 0; j < 8; ++j) v[i * 8 + j] = bf2f((unsigned short)h[j]);
    }
    float pv = INFINITY; int pi = -1;
    int gl[8];
#pragma unroll
    for (int k = 0; k < 8; ++k) {
        float bv = -INFINITY; int bi = NGRP;
#pragma unroll
        for (int i = 0; i < 32; ++i) {
            const int idx = lane * 32 + i;
            const bool after  = (v[i] < pv) || (v[i] == pv && idx > pi);
            const bool before = (v[i] > bv) || (v[i] == bv && idx < bi);
            if (after && before) { bv = v[i]; bi = idx; }
        }
#pragma unroll
        for (int off = 32; off >= 1; off >>= 1) {
            const float ov = __shfl_xor(bv, off);
            const int   oi = __shfl_xor(bi, off);
            if ((ov > bv) || (ov == bv && oi < bi)) { bv = ov; bi = oi; }
        }
        gl[k] = bi; pv = bv; pi = bi;
    }
#pragma unroll
    for (int a = 0; a < 8; ++a)
#pragma unroll
        for (int b2 = 0; b2 < 7; ++b2)
            if (gl[b2] > gl[b2 + 1]) { int t = gl[b2]; gl[b2] = gl[b2 + 1]; gl[b2 + 1] = t; }
    if (lane == 0) {
        int4 lo = make_int4(gl[0], gl[1], gl[2], gl[3]);
        int4 hi = make_int4(gl[4], gl[5], gl[6], gl[7]);
        *reinterpret_cast<int4*>(g8 + (size_t)row * 8)     = lo;
        *reinterpret_cast<int4*>(g8 + (size_t)row * 8 + 4) = hi;
    }
}

// ---------------------------------------------------------------------------
// Kernel 4: exact fp32 refine of the 32 candidates per row (unchanged).
// ---------------------------------------------------------------------------
__global__ __launch_bounds__(256)
void refine(const float* __restrict__ t_c, const float* __restrict__ t_s,
            const int* __restrict__ g8, int* __restrict__ tidx) {
    __shared__ float tc[D_S];
    __shared__ float sc[4 * PGRP];
    const int row = blockIdx.x;
    const int tid = threadIdx.x;
    *reinterpret_cast<float4*>(&tc[tid * 4]) =
        *reinterpret_cast<const float4*>(&t_c[(size_t)row * D_S + tid * 4]);
    __syncthreads();
    const int w = tid >> 6, lane = tid & 63;
    float4 c4[4];
#pragma unroll
    for (int q = 0; q < 4; ++q)
        c4[q] = *reinterpret_cast<const float4*>(&tc[lane * 16 + q * 4]);
#pragma unroll
    for (int i = 0; i < 2; ++i) {
        const int slotg = w * 2 + i;
        const int g = g8[(size_t)row * 8 + slotg];
#pragma unroll
        for (int o = 0; o < 4; ++o) {
            const int n = g * 4 + o;
            const float* ts = t_s + (size_t)n * D_S + lane * 16;
            float p = 0.f;
#pragma unroll
            for (int q = 0; q < 4; ++q) {
                const float4 tv = *reinterpret_cast<const float4*>(ts + q * 4);
                p += c4[q].x * tv.x + c4[q].y * tv.y + c4[q].z * tv.z + c4[q].w * tv.w;
            }
#pragma unroll
            for (int off = 32; off >= 1; off >>= 1) p += __shfl_xor(p, off);
            if (lane == 0) sc[slotg * 4 + o] = p;
        }
    }
    __syncthreads();
    if (tid == 0) {
        float v1 = -INFINITY, v2 = -INFINITY; int i1 = 0, i2 = 0;
#pragma unroll
        for (int s = 0; s < 4 * PGRP; ++s) {
            const int n = g8[(size_t)row * 8 + (s >> 2)] * 4 + (s & 3);
            const float v = sc[s];
            if (v > v1)      { v2 = v1; i2 = i1; v1 = v; i1 = n; }
            else if (v > v2) { v2 = v; i2 = n; }
        }
        tidx[row * 2 + 0] = i1;
        tidx[row * 2 + 1] = i2;
    }
}

// ---------------------------------------------------------------------------
// Kernel 5: gather selected transformed-srt rows (unchanged).
// ---------------------------------------------------------------------------
__global__ __launch_bounds__(256)
void gather_rows(const float* __restrict__ TS, const int* __restrict__ topIdx,
                 float* __restrict__ out) {
    const int row = blockIdx.x;
    const int src = topIdx[row];
    const int tid = threadIdx.x;
    const float4 v = *reinterpret_cast<const float4*>(&TS[(size_t)src * D_S + tid * 4]);
    *reinterpret_cast<float4*>(&out[(size_t)row * D_S + tid * 4]) = v;
}

// ---------------------------------------------------------------------------
extern "C" void kernel_launch(void* const* d_in, const int* in_sizes, int n_in,
                              void* d_out, int out_size, void* d_ws, size_t ws_size,
                              hipStream_t stream) {
    const float* srt      = (const float*)d_in[0];  // [8192,1024]
    const float* comments = (const float*)d_in[1];  // [4096,768]
    const float* Wc       = (const float*)d_in[2];  // [768,1024]
    const float* bc       = (const float*)d_in[3];  // [1024]
    const float* Ws       = (const float*)d_in[4];  // [1024,1024]
    const float* bs       = (const float*)d_in[5];  // [1024]
    float* out = (float*)d_out;

    // base workspace layout (~92.4 MB, identical to previous rounds)
    char* p = (char*)d_ws;
    float* t_c = (float*)p;          p += (size_t)B_C * D_S * 4;     // 16 MB
    float* t_s = (float*)p;          p += (size_t)N_SRT * D_S * 4;   // 32 MB
    unsigned short* tc_h = (unsigned short*)p; p += (size_t)B_C * D_S * 2;    // 8 MB
    unsigned short* ts_h = (unsigned short*)p; p += (size_t)N_SRT * D_S * 2;  // 16 MB
    unsigned short* G    = (unsigned short*)p; p += (size_t)B_C * NGRP * 2;   // 16 MB
    int* g8   = (int*)p;             p += (size_t)B_C * PGRP * 4;
    int* tidx = (int*)p;             p += (size_t)B_C * KSEL * 4;

    // bf16x6 plane workspace (appended; ~80.2 MB more)
    unsigned short* actS = (unsigned short*)p; p += 3 * (size_t)N_SRT * D_S * 2; // 50.3 MB
    unsigned short* actC = (unsigned short*)p; p += 3 * (size_t)B_C * D_C * 2;   // 18.9 MB
    unsigned short* wtS  = (unsigned short*)p; p += 3 * (size_t)D_S * D_S * 2;   // 6.3 MB
    unsigned short* wtC  = (unsigned short*)p; p += 3 * (size_t)D_S * D_C * 2;   // 4.7 MB
    const size_t required = (size_t)(p - (char*)d_ws);

    if (ws_size >= required) {
        // --- bf16x6 MFMA transform path ---
        split_act<<<(N_SRT * D_S / 8 + B_C * D_C / 8) / 256, 256, 0, stream>>>(
            srt, comments, actS, actC);
        split_w<<<dim3(D_S / 64, D_S / 64), 256, 0, stream>>>(Ws, wtS, D_S);
        split_w<<<dim3(D_S / 64, D_C / 64), 256, 0, stream>>>(Wc, wtC, D_C);

        transform_mfma<D_S><<<dim3(D_S / 128, N_SRT / 128), 256, 0, stream>>>(
            actS, wtS, bs, t_s, ts_h, (size_t)N_SRT * D_S);
        transform_mfma<D_C><<<dim3(D_S / 128, B_C / 128), 256, 0, stream>>>(
            actC, wtC, bc, t_c, tc_h, (size_t)B_C * D_C);
    } else {
        // --- fallback: round-5 verified fp32 VALU path ---
        transform_fused<<<NB0 + NB1, 256, 0, stream>>>(
            comments, Wc, bc, t_c, tc_h,
            srt,      Ws, bs, t_s, ts_h);
    }

    scores_filter<<<dim3(N_SRT / 128, B_C / 128), 256, 0, stream>>>(ts_h, tc_h, G);
    top_groups<<<B_C / 4, 256, 0, stream>>>(G, g8);
    refine<<<B_C, 256, 0, stream>>>(t_c, t_s, g8, tidx);
    gather_rows<<<B_C * KSEL, 256, 0, stream>>>(t_s, tidx, out);
}

// Round 7
// 379.045 us; speedup vs baseline: 1.2474x; 1.0851x over previous
//
#include <hip/hip_runtime.h>
#include <math.h>

#define B_C   4096   // comments
#define N_SRT 8192   // srt rows
#define D_C   768
#define D_S   1024
#define KSEL  2
#define NGRP  (N_SRT / 4)   // 2048 groups of 4 consecutive srt rows
#define PGRP  8             // groups refined per comment row (32 candidates)

typedef float    f32x4  __attribute__((ext_vector_type(4)));
typedef short    short8 __attribute__((ext_vector_type(8)));
typedef _Float16 half8  __attribute__((ext_vector_type(8)));

__device__ inline unsigned short f2bf(float f) {           // RTNE float->bf16
    unsigned u = __float_as_uint(f);
    u += 0x7FFF + ((u >> 16) & 1);
    return (unsigned short)(u >> 16);
}
__device__ inline float bf2f(unsigned short h) {
    return __uint_as_float(((unsigned)h) << 16);
}

#define GLOAD_LDS16(gsrc, ldst)                                                     \
    __builtin_amdgcn_global_load_lds(                                               \
        (const __attribute__((address_space(1))) void*)(gsrc),                      \
        (__attribute__((address_space(3))) void*)(ldst), 16, 0, 0)

// ---------------------------------------------------------------------------
// split_act: fp16 2-term split of activations. Plane0 = f16(x) (scale 1),
// plane1 = f16(2^11 * (x - plane0)) (scale 2^11). Residual <= 2^-22 |x|.
// ---------------------------------------------------------------------------
__global__ __launch_bounds__(256)
void split_act(const float* __restrict__ srt, const float* __restrict__ com,
               _Float16* __restrict__ pS, _Float16* __restrict__ pC) {
    const int g = blockIdx.x * 256 + threadIdx.x;   // one 8-elem group / thread
    const int E0 = N_SRT * D_S / 8;
    const float* src;
    _Float16* dst;
    size_t stride;
    if (g < E0) {
        src = srt + (size_t)g * 8; dst = pS + (size_t)g * 8;
        stride = (size_t)N_SRT * D_S;
    } else {
        const int g2 = g - E0;
        src = com + (size_t)g2 * 8; dst = pC + (size_t)g2 * 8;
        stride = (size_t)B_C * D_C;
    }
    const float4 a = *reinterpret_cast<const float4*>(src);
    const float4 b = *reinterpret_cast<const float4*>(src + 4);
    const float x[8] = {a.x, a.y, a.z, a.w, b.x, b.y, b.z, b.w};
    half8 hv, mv;
#pragma unroll
    for (int j = 0; j < 8; ++j) {
        const _Float16 h = (_Float16)x[j];
        const float    r = x[j] - (float)h;          // exact
        hv[j] = h; mv[j] = (_Float16)(r * 2048.0f);
    }
    *reinterpret_cast<half8*>(dst)          = hv;
    *reinterpret_cast<half8*>(dst + stride) = mv;
}

// ---------------------------------------------------------------------------
// split_w: W[k][n] -> 2 fp16 planes of W^T: Wt[p][n][k]. Plane0 = f16(2^15 W)
// (scale 2^15, keeps all weights fp16-normal), plane1 = f16(2^11 * residual)
// (scale 2^26). 64x64 LDS transpose, pad 65.
// ---------------------------------------------------------------------------
__global__ __launch_bounds__(256)
void split_w(const float* __restrict__ W, _Float16* __restrict__ Wt, int K) {
    __shared__ float t[64][65];
    const int n0 = blockIdx.x * 64, k0 = blockIdx.y * 64;
    const int tid = threadIdx.x;
    const int c = tid & 63, rq = tid >> 6;
#pragma unroll
    for (int j = 0; j < 16; ++j) {
        const int kr = rq * 16 + j;
        t[kr][c] = W[(size_t)(k0 + kr) * D_S + n0 + c];
    }
    __syncthreads();
    const size_t PS = (size_t)K * D_S;
#pragma unroll
    for (int j = 0; j < 16; ++j) {
        const int nr = rq * 16 + j;
        const float xs = t[c][nr] * 32768.0f;        // exact (pow2 scale)
        const _Float16 h = (_Float16)xs;
        const float    r = xs - (float)h;            // exact
        const size_t o = (size_t)(n0 + nr) * K + k0 + c;
        Wt[o]      = h;
        Wt[o + PS] = (_Float16)(r * 2048.0f);
    }
}

// ---------------------------------------------------------------------------
// transform_mfma<K>: C = relu(Act @ W + bias) via scaled fp16x3 emulation.
// 3 plane-pair passes: pp0 = W0*A0 -> acc1 (scale 2^15);
// pp1 = W0*A1, pp2 = W1*A0 -> acc2 (scale 2^26).
// t = 2^-15 acc1 + 2^-26 acc2 + bias. Error ~1e-7 rel (fp32 class).
// Structure: 128x128 tile, 4 waves 2x2, BK=64, XOR-swizzled global_load_lds
// staging, stage-ahead dbuf (round-6 verified), + XCD-chunked block swizzle
// (consecutive hw blocks share bm; chunking keeps them on one XCD's L2).
// ---------------------------------------------------------------------------
template<int K>
__global__ __launch_bounds__(256)
void transform_mfma(const _Float16* __restrict__ actP,  // [2][M][K]
                    const _Float16* __restrict__ wtP,   // [2][1024][K]
                    const float* __restrict__ bias,
                    float* __restrict__ C,              // [M][1024]
                    unsigned short* __restrict__ H,     // [M][1024] bf16
                    size_t aps) {                       // act plane stride
    __shared__ __align__(16) _Float16 sA[2][128 * 64];  // Wt tile
    __shared__ __align__(16) _Float16 sB[2][128 * 64];  // Act tile
    const int tid  = threadIdx.x;
    const int lane = tid & 63;
    const int w    = tid >> 6;
    const int lr   = lane & 15, lg = lane >> 4;
    const int wn   = w & 1, wc = w >> 1;

    // XCD-chunked bijective swizzle (nwg % 8 == 0: 512 or 256 blocks)
    const int nwg = gridDim.x * gridDim.y;
    const int hw  = blockIdx.y * gridDim.x + blockIdx.x;
    const int lgid = (hw & 7) * (nwg >> 3) + (hw >> 3);
    const int bn  = (lgid & 7) * 128;     // out-col tile (1024/128 = 8)
    const int bm  = (lgid >> 3) * 128;    // act-row tile

    const size_t wps = (size_t)D_S * K;

    const f32x4 vzero = {0.f, 0.f, 0.f, 0.f};
    f32x4 acc1[4][4], acc2[4][4];
#pragma unroll
    for (int i = 0; i < 4; ++i)
#pragma unroll
        for (int j = 0; j < 4; ++j) { acc1[i][j] = vzero; acc2[i][j] = vzero; }

    const int sr = tid >> 3;  // staging row within 32-row stripe
    const int sb = tid & 7;   // 16B block within 128B row

    constexpr int KC = K / 64;
    constexpr int NT = 3 * KC;

    auto stage = [&](int buf, int t) {
        const int pp = t / KC;                 // 0,1,2
        const int kb = (t - pp * KC) * 64;
        const _Float16* gA = wtP  + (size_t)(pp == 2 ? 1 : 0) * wps
                                  + (size_t)bn * K + kb;
        const _Float16* gB = actP + (size_t)(pp == 1 ? 1 : 0) * aps
                                  + (size_t)bm * K + kb;
#pragma unroll
        for (int i = 0; i < 4; ++i) {
            const int r  = i * 32 + sr;
            const int sw = (sb ^ (r & 7)) * 8;     // inverse-swizzled k offset
            GLOAD_LDS16(gA + (size_t)r * K + sw,
                        (char*)&sA[buf][0] + i * 4096 + tid * 16);
            GLOAD_LDS16(gB + (size_t)r * K + sw,
                        (char*)&sB[buf][0] + i * 4096 + tid * 16);
        }
    };

    stage(0, 0);
    __syncthreads();

    for (int t = 0; t < NT; ++t) {
        const int cur = t & 1;
        if (t + 1 < NT) stage(cur ^ 1, t + 1);
        const bool first = (t < KC);           // pp0 -> acc1, else acc2

#pragma unroll
        for (int kt = 0; kt < 2; ++kt) {
            half8 a[4], b[4];
#pragma unroll
            for (int t4 = 0; t4 < 4; ++t4) {
                const int ra = wn * 64 + t4 * 16 + lr;
                a[t4] = *(const half8*)((const char*)&sA[cur][0] + ra * 128 +
                                        (((kt * 4 + lg) ^ (ra & 7)) * 16));
                const int rb = wc * 64 + t4 * 16 + lr;
                b[t4] = *(const half8*)((const char*)&sB[cur][0] + rb * 128 +
                                        (((kt * 4 + lg) ^ (rb & 7)) * 16));
            }
            if (first) {
#pragma unroll
                for (int i = 0; i < 4; ++i)
#pragma unroll
                    for (int j = 0; j < 4; ++j)
                        acc1[i][j] = __builtin_amdgcn_mfma_f32_16x16x32_f16(
                            a[i], b[j], acc1[i][j], 0, 0, 0);
            } else {
#pragma unroll
                for (int i = 0; i < 4; ++i)
#pragma unroll
                    for (int j = 0; j < 4; ++j)
                        acc2[i][j] = __builtin_amdgcn_mfma_f32_16x16x32_f16(
                            a[i], b[j], acc2[i][j], 0, 0, 0);
            }
        }
        __syncthreads();
    }

    // epilogue: n = bn + wn*64 + i*16 + lg*4 + q;  m = bm + wc*64 + j*16 + lr
    const float s1 = 3.0517578125e-5f;          // 2^-15
    const float s2 = 1.4901161193847656e-8f;    // 2^-26
#pragma unroll
    for (int i = 0; i < 4; ++i) {
        const int n = bn + wn * 64 + i * 16 + lg * 4;
        const f32x4 bb = *reinterpret_cast<const f32x4*>(&bias[n]);
#pragma unroll
        for (int j = 0; j < 4; ++j) {
            const int m = bm + wc * 64 + j * 16 + lr;
            f32x4 o;
#pragma unroll
            for (int q = 0; q < 4; ++q)
                o[q] = fmaxf(fmaf(acc2[i][j][q], s2,
                              fmaf(acc1[i][j][q], s1, bb[q])), 0.f);
            *reinterpret_cast<f32x4*>(&C[(size_t)m * D_S + n]) = o;
            ushort4 hh;
            hh.x = f2bf(o[0]); hh.y = f2bf(o[1]);
            hh.z = f2bf(o[2]); hh.w = f2bf(o[3]);
            *reinterpret_cast<ushort4*>(&H[(size_t)m * D_S + n]) = hh;
        }
    }
}

// ---------------------------------------------------------------------------
// FALLBACK (round-5 verified): fused fp32 VALU transforms (ws too small).
// ---------------------------------------------------------------------------
#define NB0 ((B_C / 128) * (D_S / 128))     // 256
#define NB1 ((N_SRT / 128) * (D_S / 128))   // 512

__global__ __launch_bounds__(256)
void transform_fused(const float* __restrict__ A0, const float* __restrict__ W0,
                     const float* __restrict__ b0, float* __restrict__ C0,
                     unsigned short* __restrict__ H0,
                     const float* __restrict__ A1, const float* __restrict__ W1,
                     const float* __restrict__ b1, float* __restrict__ C1,
                     unsigned short* __restrict__ H1) {
    __shared__ __align__(16) float As[2][128][16];
    __shared__ __align__(16) float Bs[2][2048];

    const bool p1 = (int)blockIdx.x >= NB0;
    const int  b  = p1 ? (int)blockIdx.x - NB0 : (int)blockIdx.x;
    const float* __restrict__ A = p1 ? A1 : A0;
    const float* __restrict__ W = p1 ? W1 : W0;
    const float* __restrict__ bias = p1 ? b1 : b0;
    float* __restrict__ C = p1 ? C1 : C0;
    unsigned short* __restrict__ H = p1 ? H1 : H0;
    const int K = p1 ? D_S : D_C;

    const int bn = (b & 7) * 128;
    const int bm = (b >> 3) * 128;

    const int tid = threadIdx.x;
    const int tx = tid & 15, ty = tid >> 4;

    int a_off[2], w_off[2];
#pragma unroll
    for (int i = 0; i < 2; ++i) {
        const int idx = tid + i * 256;
        const int r = idx >> 2, q = idx & 3;
        a_off[i] = r * K + (q ^ ((r >> 3) & 3)) * 4;
        const int s = idx & 63;
        const int kloc = 2 * (idx >> 6) + ((s >> 4) & 1);
        const int cb   = 2 * (s & 15) + (s >> 5);
        w_off[i] = kloc * D_S + cb * 4;
    }

#define STAGE(bufi, k0)                                                        \
    {                                                                          \
        _Pragma("unroll")                                                      \
        for (int i = 0; i < 2; ++i) {                                          \
            const int idx = tid + i * 256;                                     \
            GLOAD_LDS16(A + (size_t)bm * K + (k0) + a_off[i],                  \
                        (char*)&As[bufi][0][0] + idx * 16);                    \
            GLOAD_LDS16(W + (size_t)(k0) * D_S + bn + w_off[i],                \
                        (char*)&Bs[bufi][0] + idx * 16);                       \
        }                                                                      \
    }

    float acc[8][8] = {};

    STAGE(0, 0);
    __syncthreads();

    const int nk = K / 16;
    for (int t = 0; t < nk; ++t) {
        const int cur = t & 1;
        if (t + 1 < nk) STAGE(t & 1 ? 0 : 1, (t + 1) * 16);

        const float* __restrict__ Bf = &Bs[cur][0];
#pragma unroll
        for (int kq = 0; kq < 4; ++kq) {
            f32x4 a4[8];
#pragma unroll
            for (int i = 0; i < 8; ++i)
                a4[i] = *reinterpret_cast<const f32x4*>(
                    &As[cur][ty * 8 + i][(kq ^ (ty & 3)) * 4]);
#pragma unroll
            for (int k2 = 0; k2 < 4; ++k2) {
                const int k = kq * 4 + k2;
                const int boff = (k >> 1) * 256 + (tx + ((k & 1) << 4)) * 4;
                const f32x4 bx = *reinterpret_cast<const f32x4*>(Bf + boff);
                const f32x4 by = *reinterpret_cast<const f32x4*>(Bf + boff + 128);
                const float bv[8] = {bx[0], bx[1], bx[2], bx[3], by[0], by[1], by[2], by[3]};
#pragma unroll
                for (int i = 0; i < 8; ++i) {
                    const float av = a4[i][k2];
#pragma unroll
                    for (int j = 0; j < 8; ++j)
                        acc[i][j] = fmaf(av, bv[j], acc[i][j]);
                }
            }
        }
        __syncthreads();
    }
#undef STAGE

    const f32x4 g0 = *reinterpret_cast<const f32x4*>(&bias[bn + tx * 8]);
    const f32x4 g1 = *reinterpret_cast<const f32x4*>(&bias[bn + tx * 8 + 4]);
#pragma unroll
    for (int i = 0; i < 8; ++i) {
        const int m = bm + ty * 8 + i;
        const int n = bn + tx * 8;
        f32x4 o0, o1;
#pragma unroll
        for (int j = 0; j < 4; ++j) {
            o0[j] = fmaxf(acc[i][j]     + g0[j], 0.f);
            o1[j] = fmaxf(acc[i][j + 4] + g1[j], 0.f);
        }
        *reinterpret_cast<f32x4*>(&C[(size_t)m * D_S + n])     = o0;
        *reinterpret_cast<f32x4*>(&C[(size_t)m * D_S + n + 4]) = o1;
        short8 h;
#pragma unroll
        for (int j = 0; j < 4; ++j) {
            h[j]     = (short)f2bf(o0[j]);
            h[j + 4] = (short)f2bf(o1[j]);
        }
        *reinterpret_cast<short8*>(&H[(size_t)m * D_S + n]) = h;
    }
}

// ---------------------------------------------------------------------------
// Kernel 2: bf16 MFMA score filter (unchanged, verified).
// ---------------------------------------------------------------------------
__global__ __launch_bounds__(256)
void scores_filter(const unsigned short* __restrict__ TSh,
                   const unsigned short* __restrict__ TCh,
                   unsigned short* __restrict__ G) {
    __shared__ __align__(16) unsigned short sA[2][128 * 64];
    __shared__ __align__(16) unsigned short sB[2][128 * 64];
    const int tid  = threadIdx.x;
    const int lane = tid & 63;
    const int w    = tid >> 6;
    const int lr   = lane & 15, lg = lane >> 4;
    const int wn   = w & 1, wc = w >> 1;
    const int n0   = blockIdx.x * 128;
    const int c0   = blockIdx.y * 128;

    const f32x4 vzero = {0.f, 0.f, 0.f, 0.f};
    f32x4 acc[4][4];
#pragma unroll
    for (int i = 0; i < 4; ++i)
#pragma unroll
        for (int j = 0; j < 4; ++j) acc[i][j] = vzero;

    const int sr = tid >> 3;
    const int sb = tid & 7;

#define FSTAGE(bufi, kb)                                                       \
    {                                                                          \
        _Pragma("unroll")                                                      \
        for (int i = 0; i < 4; ++i) {                                          \
            const int r  = i * 32 + sr;                                        \
            const int sw = (sb ^ (r & 7)) * 8;                                 \
            GLOAD_LDS16(TSh + (size_t)(n0 + r) * D_S + (kb) + sw,              \
                        (char*)&sA[bufi][0] + i * 4096 + tid * 16);            \
            GLOAD_LDS16(TCh + (size_t)(c0 + r) * D_S + (kb) + sw,              \
                        (char*)&sB[bufi][0] + i * 4096 + tid * 16);            \
        }                                                                      \
    }

    FSTAGE(0, 0);
    __syncthreads();

    for (int kc = 0; kc < 16; ++kc) {
        const int cur = kc & 1;
        if (kc + 1 < 16) FSTAGE(cur ^ 1, (kc + 1) * 64);

#pragma unroll
        for (int kt = 0; kt < 2; ++kt) {
            short8 a[4], b[4];
#pragma unroll
            for (int t = 0; t < 4; ++t) {
                const int ra = wn * 64 + t * 16 + lr;
                a[t] = *(const short8*)((const char*)&sA[cur][0] + ra * 128 +
                                        (((kt * 4 + lg) ^ (ra & 7)) * 16));
                const int rb = wc * 64 + t * 16 + lr;
                b[t] = *(const short8*)((const char*)&sB[cur][0] + rb * 128 +
                                        (((kt * 4 + lg) ^ (rb & 7)) * 16));
            }
#pragma unroll
            for (int i = 0; i < 4; ++i)
#pragma unroll
                for (int j = 0; j < 4; ++j)
                    acc[i][j] = __builtin_amdgcn_mfma_f32_16x16x32_bf16(
                        a[i], b[j], acc[i][j], 0, 0, 0);
        }
        __syncthreads();
    }
#undef FSTAGE

#pragma unroll
    for (int nt = 0; nt < 4; ++nt) {
        const int n4 = (n0 >> 2) + wn * 16 + nt * 4 + lg;
#pragma unroll
        for (int ct = 0; ct < 4; ++ct) {
            const int c = c0 + wc * 64 + ct * 16 + lr;
            const f32x4 v = acc[nt][ct];
            const float m = fmaxf(fmaxf(v.x, v.y), fmaxf(v.z, v.w));
            G[(size_t)c * NGRP + n4] = f2bf(m);
        }
    }
}

// ---------------------------------------------------------------------------
// Kernel 3: per comment row, top-8 groups by approx group-max (unchanged).
// ---------------------------------------------------------------------------
__global__ __launch_bounds__(256)
void top_groups(const unsigned short* __restrict__ G, int* __restrict__ g8) {
    const int w = threadIdx.x >> 6, lane = threadIdx.x & 63;
    const int row = blockIdx.x * 4 + w;
    float v[32];
    const unsigned short* gp = G + (size_t)row * NGRP + lane * 32;
#pragma unroll
    for (int i = 0; i < 4; ++i) {
        short8 h = *(const short8*)(gp + i * 8);
#pragma unroll
        for (int j = 0; j < 8; ++j) v[i * 8 + j] = bf2f((unsigned short)h[j]);
    }
    float pv = INFINITY; int pi = -1;
    int gl[8];
#pragma unroll
    for (int k = 0; k < 8; ++k) {
        float bv = -INFINITY; int bi = NGRP;
#pragma unroll
        for (int i = 0; i < 32; ++i) {
            const int idx = lane * 32 + i;
            const bool after  = (v[i] < pv) || (v[i] == pv && idx > pi);
            const bool before = (v[i] > bv) || (v[i] == bv && idx < bi);
            if (after && before) { bv = v[i]; bi = idx; }
        }
#pragma unroll
        for (int off = 32; off >= 1; off >>= 1) {
            const float ov = __shfl_xor(bv, off);
            const int   oi = __shfl_xor(bi, off);
            if ((ov > bv) || (ov == bv && oi < bi)) { bv = ov; bi = oi; }
        }
        gl[k] = bi; pv = bv; pi = bi;
    }
#pragma unroll
    for (int a = 0; a < 8; ++a)
#pragma unroll
        for (int b2 = 0; b2 < 7; ++b2)
            if (gl[b2] > gl[b2 + 1]) { int t = gl[b2]; gl[b2] = gl[b2 + 1]; gl[b2 + 1] = t; }
    if (lane == 0) {
        int4 lo = make_int4(gl[0], gl[1], gl[2], gl[3]);
        int4 hi = make_int4(gl[4], gl[5], gl[6], gl[7]);
        *reinterpret_cast<int4*>(g8 + (size_t)row * 8)     = lo;
        *reinterpret_cast<int4*>(g8 + (size_t)row * 8 + 4) = hi;
    }
}

// ---------------------------------------------------------------------------
// Kernel 4: exact fp32 refine of the 32 candidates per row (unchanged).
// ---------------------------------------------------------------------------
__global__ __launch_bounds__(256)
void refine(const float* __restrict__ t_c, const float* __restrict__ t_s,
            const int* __restrict__ g8, int* __restrict__ tidx) {
    __shared__ float tc[D_S];
    __shared__ float sc[4 * PGRP];
    const int row = blockIdx.x;
    const int tid = threadIdx.x;
    *reinterpret_cast<float4*>(&tc[tid * 4]) =
        *reinterpret_cast<const float4*>(&t_c[(size_t)row * D_S + tid * 4]);
    __syncthreads();
    const int w = tid >> 6, lane = tid & 63;
    float4 c4[4];
#pragma unroll
    for (int q = 0; q < 4; ++q)
        c4[q] = *reinterpret_cast<const float4*>(&tc[lane * 16 + q * 4]);
#pragma unroll
    for (int i = 0; i < 2; ++i) {
        const int slotg = w * 2 + i;
        const int g = g8[(size_t)row * 8 + slotg];
#pragma unroll
        for (int o = 0; o < 4; ++o) {
            const int n = g * 4 + o;
            const float* ts = t_s + (size_t)n * D_S + lane * 16;
            float p = 0.f;
#pragma unroll
            for (int q = 0; q < 4; ++q) {
                const float4 tv = *reinterpret_cast<const float4*>(ts + q * 4);
                p += c4[q].x * tv.x + c4[q].y * tv.y + c4[q].z * tv.z + c4[q].w * tv.w;
            }
#pragma unroll
            for (int off = 32; off >= 1; off >>= 1) p += __shfl_xor(p, off);
            if (lane == 0) sc[slotg * 4 + o] = p;
        }
    }
    __syncthreads();
    if (tid == 0) {
        float v1 = -INFINITY, v2 = -INFINITY; int i1 = 0, i2 = 0;
#pragma unroll
        for (int s = 0; s < 4 * PGRP; ++s) {
            const int n = g8[(size_t)row * 8 + (s >> 2)] * 4 + (s & 3);
            const float v = sc[s];
            if (v > v1)      { v2 = v1; i2 = i1; v1 = v; i1 = n; }
            else if (v > v2) { v2 = v; i2 = n; }
        }
        tidx[row * 2 + 0] = i1;
        tidx[row * 2 + 1] = i2;
    }
}

// ---------------------------------------------------------------------------
// Kernel 5: gather selected transformed-srt rows (unchanged).
// ---------------------------------------------------------------------------
__global__ __launch_bounds__(256)
void gather_rows(const float* __restrict__ TS, const int* __restrict__ topIdx,
                 float* __restrict__ out) {
    const int row = blockIdx.x;
    const int src = topIdx[row];
    const int tid = threadIdx.x;
    const float4 v = *reinterpret_cast<const float4*>(&TS[(size_t)src * D_S + tid * 4]);
    *reinterpret_cast<float4*>(&out[(size_t)row * D_S + tid * 4]) = v;
}

// ---------------------------------------------------------------------------
extern "C" void kernel_launch(void* const* d_in, const int* in_sizes, int n_in,
                              void* d_out, int out_size, void* d_ws, size_t ws_size,
                              hipStream_t stream) {
    const float* srt      = (const float*)d_in[0];  // [8192,1024]
    const float* comments = (const float*)d_in[1];  // [4096,768]
    const float* Wc       = (const float*)d_in[2];  // [768,1024]
    const float* bc       = (const float*)d_in[3];  // [1024]
    const float* Ws       = (const float*)d_in[4];  // [1024,1024]
    const float* bs       = (const float*)d_in[5];  // [1024]
    float* out = (float*)d_out;

    // base workspace layout (identical to previous rounds)
    char* p = (char*)d_ws;
    float* t_c = (float*)p;          p += (size_t)B_C * D_S * 4;     // 16 MB
    float* t_s = (float*)p;          p += (size_t)N_SRT * D_S * 4;   // 32 MB
    unsigned short* tc_h = (unsigned short*)p; p += (size_t)B_C * D_S * 2;    // 8 MB
    unsigned short* ts_h = (unsigned short*)p; p += (size_t)N_SRT * D_S * 2;  // 16 MB
    unsigned short* G    = (unsigned short*)p; p += (size_t)B_C * NGRP * 2;   // 16 MB
    int* g8   = (int*)p;             p += (size_t)B_C * PGRP * 4;
    int* tidx = (int*)p;             p += (size_t)B_C * KSEL * 4;

    // fp16 2-plane workspace (appended; ~53.4 MB)
    _Float16* actS = (_Float16*)p; p += 2 * (size_t)N_SRT * D_S * 2; // 33.5 MB
    _Float16* actC = (_Float16*)p; p += 2 * (size_t)B_C * D_C * 2;   // 12.6 MB
    _Float16* wtS  = (_Float16*)p; p += 2 * (size_t)D_S * D_S * 2;   // 4.2 MB
    _Float16* wtC  = (_Float16*)p; p += 2 * (size_t)D_S * D_C * 2;   // 3.1 MB
    const size_t required = (size_t)(p - (char*)d_ws);

    if (ws_size >= required) {
        // --- scaled fp16x3 MFMA transform path ---
        split_act<<<(N_SRT * D_S / 8 + B_C * D_C / 8) / 256, 256, 0, stream>>>(
            srt, comments, actS, actC);
        split_w<<<dim3(D_S / 64, D_S / 64), 256, 0, stream>>>(Ws, wtS, D_S);
        split_w<<<dim3(D_S / 64, D_C / 64), 256, 0, stream>>>(Wc, wtC, D_C);

        transform_mfma<D_S><<<dim3(D_S / 128, N_SRT / 128), 256, 0, stream>>>(
            actS, wtS, bs, t_s, ts_h, (size_t)N_SRT * D_S);
        transform_mfma<D_C><<<dim3(D_S / 128, B_C / 128), 256, 0, stream>>>(
            actC, wtC, bc, t_c, tc_h, (size_t)B_C * D_C);
    } else {
        // --- fallback: round-5 verified fp32 VALU path ---
        transform_fused<<<NB0 + NB1, 256, 0, stream>>>(
            comments, Wc, bc, t_c, tc_h,
            srt,      Ws, bs, t_s, ts_h);
    }

    scores_filter<<<dim3(N_SRT / 128, B_C / 128), 256, 0, stream>>>(ts_h, tc_h, G);
    top_groups<<<B_C / 4, 256, 0, stream>>>(G, g8);
    refine<<<B_C, 256, 0, stream>>>(t_c, t_s, g8, tidx);
    gather_rows<<<B_C * KSEL, 256, 0, stream>>>(t_s, tidx, out);
}

// Round 8
// 306.159 us; speedup vs baseline: 1.5443x; 1.2381x over previous
//
#include <hip/hip_runtime.h>
#include <math.h>

#define B_C   4096   // comments
#define N_SRT 8192   // srt rows
#define D_C   768
#define D_S   1024
#define KSEL  2
#define NGRP  (N_SRT / 4)   // 2048 groups of 4 consecutive srt rows
#define PGRP  8             // groups refined per comment row (32 candidates)

typedef float    f32x4  __attribute__((ext_vector_type(4)));
typedef short    short8 __attribute__((ext_vector_type(8)));
typedef _Float16 half8  __attribute__((ext_vector_type(8)));

__device__ inline unsigned short f2bf(float f) {           // RTNE float->bf16
    unsigned u = __float_as_uint(f);
    u += 0x7FFF + ((u >> 16) & 1);
    return (unsigned short)(u >> 16);
}
__device__ inline float bf2f(unsigned short h) {
    return __uint_as_float(((unsigned)h) << 16);
}

#define GLOAD_LDS16(gsrc, ldst)                                                     \
    __builtin_amdgcn_global_load_lds(                                               \
        (const __attribute__((address_space(1))) void*)(gsrc),                      \
        (__attribute__((address_space(3))) void*)(ldst), 16, 0, 0)

// ---------------------------------------------------------------------------
// split_act: fp16 2-term split of activations. Plane0 = f16(x) (scale 1),
// plane1 = f16(2^11 * (x - plane0)) (scale 2^11). Residual <= 2^-22 |x|.
// ---------------------------------------------------------------------------
__global__ __launch_bounds__(256)
void split_act(const float* __restrict__ srt, const float* __restrict__ com,
               _Float16* __restrict__ pS, _Float16* __restrict__ pC) {
    const int g = blockIdx.x * 256 + threadIdx.x;   // one 8-elem group / thread
    const int E0 = N_SRT * D_S / 8;
    const float* src;
    _Float16* dst;
    size_t stride;
    if (g < E0) {
        src = srt + (size_t)g * 8; dst = pS + (size_t)g * 8;
        stride = (size_t)N_SRT * D_S;
    } else {
        const int g2 = g - E0;
        src = com + (size_t)g2 * 8; dst = pC + (size_t)g2 * 8;
        stride = (size_t)B_C * D_C;
    }
    const float4 a = *reinterpret_cast<const float4*>(src);
    const float4 b = *reinterpret_cast<const float4*>(src + 4);
    const float x[8] = {a.x, a.y, a.z, a.w, b.x, b.y, b.z, b.w};
    half8 hv, mv;
#pragma unroll
    for (int j = 0; j < 8; ++j) {
        const _Float16 h = (_Float16)x[j];
        const float    r = x[j] - (float)h;          // exact
        hv[j] = h; mv[j] = (_Float16)(r * 2048.0f);
    }
    *reinterpret_cast<half8*>(dst)          = hv;
    *reinterpret_cast<half8*>(dst + stride) = mv;
}

// ---------------------------------------------------------------------------
// split_w: W[k][n] -> 2 fp16 planes of W^T: Wt[p][n][k]. Plane0 = f16(2^15 W)
// (scale 2^15, keeps all weights fp16-normal), plane1 = f16(2^11 * residual)
// (scale 2^26). 64x64 LDS transpose, pad 65.
// ---------------------------------------------------------------------------
__global__ __launch_bounds__(256)
void split_w(const float* __restrict__ W, _Float16* __restrict__ Wt, int K) {
    __shared__ float t[64][65];
    const int n0 = blockIdx.x * 64, k0 = blockIdx.y * 64;
    const int tid = threadIdx.x;
    const int c = tid & 63, rq = tid >> 6;
#pragma unroll
    for (int j = 0; j < 16; ++j) {
        const int kr = rq * 16 + j;
        t[kr][c] = W[(size_t)(k0 + kr) * D_S + n0 + c];
    }
    __syncthreads();
    const size_t PS = (size_t)K * D_S;
#pragma unroll
    for (int j = 0; j < 16; ++j) {
        const int nr = rq * 16 + j;
        const float xs = t[c][nr] * 32768.0f;        // exact (pow2 scale)
        const _Float16 h = (_Float16)xs;
        const float    r = xs - (float)h;            // exact
        const size_t o = (size_t)(n0 + nr) * K + k0 + c;
        Wt[o]      = h;
        Wt[o + PS] = (_Float16)(r * 2048.0f);
    }
}

// ---------------------------------------------------------------------------
// transform_mfma_all: BOTH transforms in one 768-block launch.
// Blocks [0,512) -> srt (K=1024), [512,768) -> comments (K=768); per-segment
// XCD-chunked swizzle => each XCD gets 64 srt + 32 com blocks (balanced) with
// contiguous bm ranges (L2 reuse). Co-residency (2 blocks/CU, cross-segment)
// hides the per-step barrier drain that round 7 exposed at 1 block/CU.
//
// Numerics (scaled fp16x3, SINGLE accumulator): pp0 = W0*(2^11*A0),
// pp1 = W0*A1, pp2 = W1*A0 — all products at scale 2^26 (fp32 acc is
// scale-invariant; in-register pow2 scaling of A0 is exact, max ~11k < 65504).
// t = 2^-26*acc + bias. One acc set = 64 AGPRs (not 128) -> 2 blocks/CU.
// ---------------------------------------------------------------------------
__global__ __launch_bounds__(256)
void transform_mfma_all(const _Float16* __restrict__ actS,
                        const _Float16* __restrict__ wtS,
                        const float* __restrict__ bS,
                        float* __restrict__ CS, unsigned short* __restrict__ HS,
                        const _Float16* __restrict__ actC,
                        const _Float16* __restrict__ wtC,
                        const float* __restrict__ bC,
                        float* __restrict__ CC, unsigned short* __restrict__ HC) {
    __shared__ __align__(16) _Float16 sA[2][128 * 64];  // Wt tile (16KB each)
    __shared__ __align__(16) _Float16 sB[2][128 * 64];  // Act tile
    const int tid  = threadIdx.x;
    const int lane = tid & 63;
    const int w    = tid >> 6;
    const int lr   = lane & 15, lg = lane >> 4;
    const int wn   = w & 1, wc = w >> 1;

    // per-segment XCD-chunked bijective swizzle (512%8==0, 256%8==0)
    const int hw = blockIdx.x;
    int lgid, seg;
    if (hw < 512) { seg = 0; lgid = (hw & 7) * 64 + (hw >> 3); }
    else          { const int h2 = hw - 512; seg = 1; lgid = (h2 & 7) * 32 + (h2 >> 3); }

    const _Float16* __restrict__ actP = seg ? actC : actS;
    const _Float16* __restrict__ wtP  = seg ? wtC  : wtS;
    const float* __restrict__ bias    = seg ? bC   : bS;
    float* __restrict__ C             = seg ? CC   : CS;
    unsigned short* __restrict__ H    = seg ? HC   : HS;
    const int K   = seg ? D_C : D_S;
    const int KC  = seg ? (D_C / 64) : (D_S / 64);    // 12 : 16
    const size_t aps = seg ? (size_t)B_C * D_C : (size_t)N_SRT * D_S;
    const size_t wps = (size_t)D_S * K;

    const int bn = (lgid & 7) * 128;      // out-col tile
    const int bm = (lgid >> 3) * 128;     // act-row tile

    const f32x4 vzero = {0.f, 0.f, 0.f, 0.f};
    f32x4 acc[4][4];
#pragma unroll
    for (int i = 0; i < 4; ++i)
#pragma unroll
        for (int j = 0; j < 4; ++j) acc[i][j] = vzero;

    const int sr = tid >> 3;  // staging row within 32-row stripe
    const int sb = tid & 7;   // 16B block within 128B row

    const int NT = 3 * KC;

    auto stage = [&](int buf, int t) {
        const int pp = (t >= KC) + (t >= 2 * KC);    // 0,1,2
        const int kb = (t - pp * KC) * 64;
        const _Float16* gA = wtP  + (pp == 2 ? wps : 0) + (size_t)bn * K + kb;
        const _Float16* gB = actP + (pp == 1 ? aps : 0) + (size_t)bm * K + kb;
#pragma unroll
        for (int i = 0; i < 4; ++i) {
            const int r  = i * 32 + sr;
            const int sw = (sb ^ (r & 7)) * 8;       // inverse-swizzled k offset
            GLOAD_LDS16(gA + (size_t)r * K + sw,
                        (char*)&sA[buf][0] + i * 4096 + tid * 16);
            GLOAD_LDS16(gB + (size_t)r * K + sw,
                        (char*)&sB[buf][0] + i * 4096 + tid * 16);
        }
    };

    stage(0, 0);
    __syncthreads();

    for (int t = 0; t < NT; ++t) {
        const int cur = t & 1;
        if (t + 1 < NT) stage(cur ^ 1, t + 1);
        const bool first = (t < KC);     // pp0: scale act frags by 2^11

#pragma unroll
        for (int kt = 0; kt < 2; ++kt) {
            half8 a[4], b[4];
#pragma unroll
            for (int t4 = 0; t4 < 4; ++t4) {
                const int ra = wn * 64 + t4 * 16 + lr;
                a[t4] = *(const half8*)((const char*)&sA[cur][0] + ra * 128 +
                                        (((kt * 4 + lg) ^ (ra & 7)) * 16));
                const int rb = wc * 64 + t4 * 16 + lr;
                b[t4] = *(const half8*)((const char*)&sB[cur][0] + rb * 128 +
                                        (((kt * 4 + lg) ^ (rb & 7)) * 16));
            }
            if (first) {
#pragma unroll
                for (int t4 = 0; t4 < 4; ++t4)
                    b[t4] = b[t4] * (_Float16)2048.0f;   // exact pow2
            }
#pragma unroll
            for (int i = 0; i < 4; ++i)
#pragma unroll
                for (int j = 0; j < 4; ++j)
                    acc[i][j] = __builtin_amdgcn_mfma_f32_16x16x32_f16(
                        a[i], b[j], acc[i][j], 0, 0, 0);
        }
        __syncthreads();
    }

    // epilogue: n = bn + wn*64 + i*16 + lg*4 + q;  m = bm + wc*64 + j*16 + lr
    const float s2 = 1.4901161193847656e-8f;    // 2^-26
#pragma unroll
    for (int i = 0; i < 4; ++i) {
        const int n = bn + wn * 64 + i * 16 + lg * 4;
        const f32x4 bb = *reinterpret_cast<const f32x4*>(&bias[n]);
#pragma unroll
        for (int j = 0; j < 4; ++j) {
            const int m = bm + wc * 64 + j * 16 + lr;
            f32x4 o;
#pragma unroll
            for (int q = 0; q < 4; ++q)
                o[q] = fmaxf(fmaf(acc[i][j][q], s2, bb[q]), 0.f);
            *reinterpret_cast<f32x4*>(&C[(size_t)m * D_S + n]) = o;
            ushort4 hh;
            hh.x = f2bf(o[0]); hh.y = f2bf(o[1]);
            hh.z = f2bf(o[2]); hh.w = f2bf(o[3]);
            *reinterpret_cast<ushort4*>(&H[(size_t)m * D_S + n]) = hh;
        }
    }
}

// ---------------------------------------------------------------------------
// FALLBACK (round-5 verified): fused fp32 VALU transforms (ws too small).
// ---------------------------------------------------------------------------
#define NB0 ((B_C / 128) * (D_S / 128))     // 256
#define NB1 ((N_SRT / 128) * (D_S / 128))   // 512

__global__ __launch_bounds__(256)
void transform_fused(const float* __restrict__ A0, const float* __restrict__ W0,
                     const float* __restrict__ b0, float* __restrict__ C0,
                     unsigned short* __restrict__ H0,
                     const float* __restrict__ A1, const float* __restrict__ W1,
                     const float* __restrict__ b1, float* __restrict__ C1,
                     unsigned short* __restrict__ H1) {
    __shared__ __align__(16) float As[2][128][16];
    __shared__ __align__(16) float Bs[2][2048];

    const bool p1 = (int)blockIdx.x >= NB0;
    const int  b  = p1 ? (int)blockIdx.x - NB0 : (int)blockIdx.x;
    const float* __restrict__ A = p1 ? A1 : A0;
    const float* __restrict__ W = p1 ? W1 : W0;
    const float* __restrict__ bias = p1 ? b1 : b0;
    float* __restrict__ C = p1 ? C1 : C0;
    unsigned short* __restrict__ H = p1 ? H1 : H0;
    const int K = p1 ? D_S : D_C;

    const int bn = (b & 7) * 128;
    const int bm = (b >> 3) * 128;

    const int tid = threadIdx.x;
    const int tx = tid & 15, ty = tid >> 4;

    int a_off[2], w_off[2];
#pragma unroll
    for (int i = 0; i < 2; ++i) {
        const int idx = tid + i * 256;
        const int r = idx >> 2, q = idx & 3;
        a_off[i] = r * K + (q ^ ((r >> 3) & 3)) * 4;
        const int s = idx & 63;
        const int kloc = 2 * (idx >> 6) + ((s >> 4) & 1);
        const int cb   = 2 * (s & 15) + (s >> 5);
        w_off[i] = kloc * D_S + cb * 4;
    }

#define STAGE(bufi, k0)                                                        \
    {                                                                          \
        _Pragma("unroll")                                                      \
        for (int i = 0; i < 2; ++i) {                                          \
            const int idx = tid + i * 256;                                     \
            GLOAD_LDS16(A + (size_t)bm * K + (k0) + a_off[i],                  \
                        (char*)&As[bufi][0][0] + idx * 16);                    \
            GLOAD_LDS16(W + (size_t)(k0) * D_S + bn + w_off[i],                \
                        (char*)&Bs[bufi][0] + idx * 16);                       \
        }                                                                      \
    }

    float acc[8][8] = {};

    STAGE(0, 0);
    __syncthreads();

    const int nk = K / 16;
    for (int t = 0; t < nk; ++t) {
        const int cur = t & 1;
        if (t + 1 < nk) STAGE(t & 1 ? 0 : 1, (t + 1) * 16);

        const float* __restrict__ Bf = &Bs[cur][0];
#pragma unroll
        for (int kq = 0; kq < 4; ++kq) {
            f32x4 a4[8];
#pragma unroll
            for (int i = 0; i < 8; ++i)
                a4[i] = *reinterpret_cast<const f32x4*>(
                    &As[cur][ty * 8 + i][(kq ^ (ty & 3)) * 4]);
#pragma unroll
            for (int k2 = 0; k2 < 4; ++k2) {
                const int k = kq * 4 + k2;
                const int boff = (k >> 1) * 256 + (tx + ((k & 1) << 4)) * 4;
                const f32x4 bx = *reinterpret_cast<const f32x4*>(Bf + boff);
                const f32x4 by = *reinterpret_cast<const f32x4*>(Bf + boff + 128);
                const float bv[8] = {bx[0], bx[1], bx[2], bx[3], by[0], by[1], by[2], by[3]};
#pragma unroll
                for (int i = 0; i < 8; ++i) {
                    const float av = a4[i][k2];
#pragma unroll
                    for (int j = 0; j < 8; ++j)
                        acc[i][j] = fmaf(av, bv[j], acc[i][j]);
                }
            }
        }
        __syncthreads();
    }
#undef STAGE

    const f32x4 g0 = *reinterpret_cast<const f32x4*>(&bias[bn + tx * 8]);
    const f32x4 g1 = *reinterpret_cast<const f32x4*>(&bias[bn + tx * 8 + 4]);
#pragma unroll
    for (int i = 0; i < 8; ++i) {
        const int m = bm + ty * 8 + i;
        const int n = bn + tx * 8;
        f32x4 o0, o1;
#pragma unroll
        for (int j = 0; j < 4; ++j) {
            o0[j] = fmaxf(acc[i][j]     + g0[j], 0.f);
            o1[j] = fmaxf(acc[i][j + 4] + g1[j], 0.f);
        }
        *reinterpret_cast<f32x4*>(&C[(size_t)m * D_S + n])     = o0;
        *reinterpret_cast<f32x4*>(&C[(size_t)m * D_S + n + 4]) = o1;
        short8 h;
#pragma unroll
        for (int j = 0; j < 4; ++j) {
            h[j]     = (short)f2bf(o0[j]);
            h[j + 4] = (short)f2bf(o1[j]);
        }
        *reinterpret_cast<short8*>(&H[(size_t)m * D_S + n]) = h;
    }
}

// ---------------------------------------------------------------------------
// Kernel 2: bf16 MFMA score filter (unchanged, verified).
// ---------------------------------------------------------------------------
__global__ __launch_bounds__(256)
void scores_filter(const unsigned short* __restrict__ TSh,
                   const unsigned short* __restrict__ TCh,
                   unsigned short* __restrict__ G) {
    __shared__ __align__(16) unsigned short sA[2][128 * 64];
    __shared__ __align__(16) unsigned short sB[2][128 * 64];
    const int tid  = threadIdx.x;
    const int lane = tid & 63;
    const int w    = tid >> 6;
    const int lr   = lane & 15, lg = lane >> 4;
    const int wn   = w & 1, wc = w >> 1;
    const int n0   = blockIdx.x * 128;
    const int c0   = blockIdx.y * 128;

    const f32x4 vzero = {0.f, 0.f, 0.f, 0.f};
    f32x4 acc[4][4];
#pragma unroll
    for (int i = 0; i < 4; ++i)
#pragma unroll
        for (int j = 0; j < 4; ++j) acc[i][j] = vzero;

    const int sr = tid >> 3;
    const int sb = tid & 7;

#define FSTAGE(bufi, kb)                                                       \
    {                                                                          \
        _Pragma("unroll")                                                      \
        for (int i = 0; i < 4; ++i) {                                          \
            const int r  = i * 32 + sr;                                        \
            const int sw = (sb ^ (r & 7)) * 8;                                 \
            GLOAD_LDS16(TSh + (size_t)(n0 + r) * D_S + (kb) + sw,              \
                        (char*)&sA[bufi][0] + i * 4096 + tid * 16);            \
            GLOAD_LDS16(TCh + (size_t)(c0 + r) * D_S + (kb) + sw,              \
                        (char*)&sB[bufi][0] + i * 4096 + tid * 16);            \
        }                                                                      \
    }

    FSTAGE(0, 0);
    __syncthreads();

    for (int kc = 0; kc < 16; ++kc) {
        const int cur = kc & 1;
        if (kc + 1 < 16) FSTAGE(cur ^ 1, (kc + 1) * 64);

#pragma unroll
        for (int kt = 0; kt < 2; ++kt) {
            short8 a[4], b[4];
#pragma unroll
            for (int t = 0; t < 4; ++t) {
                const int ra = wn * 64 + t * 16 + lr;
                a[t] = *(const short8*)((const char*)&sA[cur][0] + ra * 128 +
                                        (((kt * 4 + lg) ^ (ra & 7)) * 16));
                const int rb = wc * 64 + t * 16 + lr;
                b[t] = *(const short8*)((const char*)&sB[cur][0] + rb * 128 +
                                        (((kt * 4 + lg) ^ (rb & 7)) * 16));
            }
#pragma unroll
            for (int i = 0; i < 4; ++i)
#pragma unroll
                for (int j = 0; j < 4; ++j)
                    acc[i][j] = __builtin_amdgcn_mfma_f32_16x16x32_bf16(
                        a[i], b[j], acc[i][j], 0, 0, 0);
        }
        __syncthreads();
    }
#undef FSTAGE

#pragma unroll
    for (int nt = 0; nt < 4; ++nt) {
        const int n4 = (n0 >> 2) + wn * 16 + nt * 4 + lg;
#pragma unroll
        for (int ct = 0; ct < 4; ++ct) {
            const int c = c0 + wc * 64 + ct * 16 + lr;
            const f32x4 v = acc[nt][ct];
            const float m = fmaxf(fmaxf(v.x, v.y), fmaxf(v.z, v.w));
            G[(size_t)c * NGRP + n4] = f2bf(m);
        }
    }
}

// ---------------------------------------------------------------------------
// Kernel 3: per comment row, top-8 groups by approx group-max (unchanged).
// ---------------------------------------------------------------------------
__global__ __launch_bounds__(256)
void top_groups(const unsigned short* __restrict__ G, int* __restrict__ g8) {
    const int w = threadIdx.x >> 6, lane = threadIdx.x & 63;
    const int row = blockIdx.x * 4 + w;
    float v[32];
    const unsigned short* gp = G + (size_t)row * NGRP + lane * 32;
#pragma unroll
    for (int i = 0; i < 4; ++i) {
        short8 h = *(const short8*)(gp + i * 8);
#pragma unroll
        for (int j = 0; j < 8; ++j) v[i * 8 + j] = bf2f((unsigned short)h[j]);
    }
    float pv = INFINITY; int pi = -1;
    int gl[8];
#pragma unroll
    for (int k = 0; k < 8; ++k) {
        float bv = -INFINITY; int bi = NGRP;
#pragma unroll
        for (int i = 0; i < 32; ++i) {
            const int idx = lane * 32 + i;
            const bool after  = (v[i] < pv) || (v[i] == pv && idx > pi);
            const bool before = (v[i] > bv) || (v[i] == bv && idx < bi);
            if (after && before) { bv = v[i]; bi = idx; }
        }
#pragma unroll
        for (int off = 32; off >= 1; off >>= 1) {
            const float ov = __shfl_xor(bv, off);
            const int   oi = __shfl_xor(bi, off);
            if ((ov > bv) || (ov == bv && oi < bi)) { bv = ov; bi = oi; }
        }
        gl[k] = bi; pv = bv; pi = bi;
    }
#pragma unroll
    for (int a = 0; a < 8; ++a)
#pragma unroll
        for (int b2 = 0; b2 < 7; ++b2)
            if (gl[b2] > gl[b2 + 1]) { int t = gl[b2]; gl[b2] = gl[b2 + 1]; gl[b2 + 1] = t; }
    if (lane == 0) {
        int4 lo = make_int4(gl[0], gl[1], gl[2], gl[3]);
        int4 hi = make_int4(gl[4], gl[5], gl[6], gl[7]);
        *reinterpret_cast<int4*>(g8 + (size_t)row * 8)     = lo;
        *reinterpret_cast<int4*>(g8 + (size_t)row * 8 + 4) = hi;
    }
}

// ---------------------------------------------------------------------------
// Kernel 4: exact fp32 refine of the 32 candidates per row (unchanged).
// ---------------------------------------------------------------------------
__global__ __launch_bounds__(256)
void refine(const float* __restrict__ t_c, const float* __restrict__ t_s,
            const int* __restrict__ g8, int* __restrict__ tidx) {
    __shared__ float tc[D_S];
    __shared__ float sc[4 * PGRP];
    const int row = blockIdx.x;
    const int tid = threadIdx.x;
    *reinterpret_cast<float4*>(&tc[tid * 4]) =
        *reinterpret_cast<const float4*>(&t_c[(size_t)row * D_S + tid * 4]);
    __syncthreads();
    const int w = tid >> 6, lane = tid & 63;
    float4 c4[4];
#pragma unroll
    for (int q = 0; q < 4; ++q)
        c4[q] = *reinterpret_cast<const float4*>(&tc[lane * 16 + q * 4]);
#pragma unroll
    for (int i = 0; i < 2; ++i) {
        const int slotg = w * 2 + i;
        const int g = g8[(size_t)row * 8 + slotg];
#pragma unroll
        for (int o = 0; o < 4; ++o) {
            const int n = g * 4 + o;
            const float* ts = t_s + (size_t)n * D_S + lane * 16;
            float p = 0.f;
#pragma unroll
            for (int q = 0; q < 4; ++q) {
                const float4 tv = *reinterpret_cast<const float4*>(ts + q * 4);
                p += c4[q].x * tv.x + c4[q].y * tv.y + c4[q].z * tv.z + c4[q].w * tv.w;
            }
#pragma unroll
            for (int off = 32; off >= 1; off >>= 1) p += __shfl_xor(p, off);
            if (lane == 0) sc[slotg * 4 + o] = p;
        }
    }
    __syncthreads();
    if (tid == 0) {
        float v1 = -INFINITY, v2 = -INFINITY; int i1 = 0, i2 = 0;
#pragma unroll
        for (int s = 0; s < 4 * PGRP; ++s) {
            const int n = g8[(size_t)row * 8 + (s >> 2)] * 4 + (s & 3);
            const float v = sc[s];
            if (v > v1)      { v2 = v1; i2 = i1; v1 = v; i1 = n; }
            else if (v > v2) { v2 = v; i2 = n; }
        }
        tidx[row * 2 + 0] = i1;
        tidx[row * 2 + 1] = i2;
    }
}

// ---------------------------------------------------------------------------
// Kernel 5: gather selected transformed-srt rows (unchanged).
// ---------------------------------------------------------------------------
__global__ __launch_bounds__(256)
void gather_rows(const float* __restrict__ TS, const int* __restrict__ topIdx,
                 float* __restrict__ out) {
    const int row = blockIdx.x;
    const int src = topIdx[row];
    const int tid = threadIdx.x;
    const float4 v = *reinterpret_cast<const float4*>(&TS[(size_t)src * D_S + tid * 4]);
    *reinterpret_cast<float4*>(&out[(size_t)row * D_S + tid * 4]) = v;
}

// ---------------------------------------------------------------------------
extern "C" void kernel_launch(void* const* d_in, const int* in_sizes, int n_in,
                              void* d_out, int out_size, void* d_ws, size_t ws_size,
                              hipStream_t stream) {
    const float* srt      = (const float*)d_in[0];  // [8192,1024]
    const float* comments = (const float*)d_in[1];  // [4096,768]
    const float* Wc       = (const float*)d_in[2];  // [768,1024]
    const float* bc       = (const float*)d_in[3];  // [1024]
    const float* Ws       = (const float*)d_in[4];  // [1024,1024]
    const float* bs       = (const float*)d_in[5];  // [1024]
    float* out = (float*)d_out;

    // base workspace layout (identical to previous rounds)
    char* p = (char*)d_ws;
    float* t_c = (float*)p;          p += (size_t)B_C * D_S * 4;     // 16 MB
    float* t_s = (float*)p;          p += (size_t)N_SRT * D_S * 4;   // 32 MB
    unsigned short* tc_h = (unsigned short*)p; p += (size_t)B_C * D_S * 2;    // 8 MB
    unsigned short* ts_h = (unsigned short*)p; p += (size_t)N_SRT * D_S * 2;  // 16 MB
    unsigned short* G    = (unsigned short*)p; p += (size_t)B_C * NGRP * 2;   // 16 MB
    int* g8   = (int*)p;             p += (size_t)B_C * PGRP * 4;
    int* tidx = (int*)p;             p += (size_t)B_C * KSEL * 4;

    // fp16 2-plane workspace (appended; ~53.4 MB)
    _Float16* actS = (_Float16*)p; p += 2 * (size_t)N_SRT * D_S * 2; // 33.5 MB
    _Float16* actC = (_Float16*)p; p += 2 * (size_t)B_C * D_C * 2;   // 12.6 MB
    _Float16* wtS  = (_Float16*)p; p += 2 * (size_t)D_S * D_S * 2;   // 4.2 MB
    _Float16* wtC  = (_Float16*)p; p += 2 * (size_t)D_S * D_C * 2;   // 3.1 MB
    const size_t required = (size_t)(p - (char*)d_ws);

    if (ws_size >= required) {
        // --- scaled fp16x3 MFMA transform path (single fused launch) ---
        split_act<<<(N_SRT * D_S / 8 + B_C * D_C / 8) / 256, 256, 0, stream>>>(
            srt, comments, actS, actC);
        split_w<<<dim3(D_S / 64, D_S / 64), 256, 0, stream>>>(Ws, wtS, D_S);
        split_w<<<dim3(D_S / 64, D_C / 64), 256, 0, stream>>>(Wc, wtC, D_C);

        transform_mfma_all<<<512 + 256, 256, 0, stream>>>(
            actS, wtS, bs, t_s, ts_h,
            actC, wtC, bc, t_c, tc_h);
    } else {
        // --- fallback: round-5 verified fp32 VALU path ---
        transform_fused<<<NB0 + NB1, 256, 0, stream>>>(
            comments, Wc, bc, t_c, tc_h,
            srt,      Ws, bs, t_s, ts_h);
    }

    scores_filter<<<dim3(N_SRT / 128, B_C / 128), 256, 0, stream>>>(ts_h, tc_h, G);
    top_groups<<<B_C / 4, 256, 0, stream>>>(G, g8);
    refine<<<B_C, 256, 0, stream>>>(t_c, t_s, g8, tidx);
    gather_rows<<<B_C * KSEL, 256, 0, stream>>>(t_s, tidx, out);
}

// Round 9
// 300.109 us; speedup vs baseline: 1.5754x; 1.0202x over previous
//
#include <hip/hip_runtime.h>
#include <math.h>

#define B_C   4096   // comments
#define N_SRT 8192   // srt rows
#define D_C   768
#define D_S   1024
#define KSEL  2
#define NGRP  (N_SRT / 4)   // 2048 groups of 4 consecutive srt rows
#define PGRP  8             // groups refined per comment row (32 candidates)

typedef float    f32x4  __attribute__((ext_vector_type(4)));
typedef short    short8 __attribute__((ext_vector_type(8)));
typedef _Float16 half8  __attribute__((ext_vector_type(8)));

__device__ inline unsigned short f2bf(float f) {           // RTNE float->bf16
    unsigned u = __float_as_uint(f);
    u += 0x7FFF + ((u >> 16) & 1);
    return (unsigned short)(u >> 16);
}
__device__ inline float bf2f(unsigned short h) {
    return __uint_as_float(((unsigned)h) << 16);
}

#define GLOAD_LDS16(gsrc, ldst)                                                     \
    __builtin_amdgcn_global_load_lds(                                               \
        (const __attribute__((address_space(1))) void*)(gsrc),                      \
        (__attribute__((address_space(3))) void*)(ldst), 16, 0, 0)

// ---------------------------------------------------------------------------
// split_act: fp16 2-term split of activations. Plane0 = f16(x) (scale 1),
// plane1 = f16(2^11 * (x - plane0)) (scale 2^11). Residual <= 2^-22 |x|.
// ---------------------------------------------------------------------------
__global__ __launch_bounds__(256)
void split_act(const float* __restrict__ srt, const float* __restrict__ com,
               _Float16* __restrict__ pS, _Float16* __restrict__ pC) {
    const int g = blockIdx.x * 256 + threadIdx.x;   // one 8-elem group / thread
    const int E0 = N_SRT * D_S / 8;
    const float* src;
    _Float16* dst;
    size_t stride;
    if (g < E0) {
        src = srt + (size_t)g * 8; dst = pS + (size_t)g * 8;
        stride = (size_t)N_SRT * D_S;
    } else {
        const int g2 = g - E0;
        src = com + (size_t)g2 * 8; dst = pC + (size_t)g2 * 8;
        stride = (size_t)B_C * D_C;
    }
    const float4 a = *reinterpret_cast<const float4*>(src);
    const float4 b = *reinterpret_cast<const float4*>(src + 4);
    const float x[8] = {a.x, a.y, a.z, a.w, b.x, b.y, b.z, b.w};
    half8 hv, mv;
#pragma unroll
    for (int j = 0; j < 8; ++j) {
        const _Float16 h = (_Float16)x[j];
        const float    r = x[j] - (float)h;          // exact
        hv[j] = h; mv[j] = (_Float16)(r * 2048.0f);
    }
    *reinterpret_cast<half8*>(dst)          = hv;
    *reinterpret_cast<half8*>(dst + stride) = mv;
}

// ---------------------------------------------------------------------------
// split_w: W[k][n] -> 2 fp16 planes of W^T: Wt[p][n][k]. Plane0 = f16(2^15 W)
// (scale 2^15, keeps all weights fp16-normal), plane1 = f16(2^11 * residual)
// (scale 2^26). 64x64 LDS transpose, pad 65.
// ---------------------------------------------------------------------------
__global__ __launch_bounds__(256)
void split_w(const float* __restrict__ W, _Float16* __restrict__ Wt, int K) {
    __shared__ float t[64][65];
    const int n0 = blockIdx.x * 64, k0 = blockIdx.y * 64;
    const int tid = threadIdx.x;
    const int c = tid & 63, rq = tid >> 6;
#pragma unroll
    for (int j = 0; j < 16; ++j) {
        const int kr = rq * 16 + j;
        t[kr][c] = W[(size_t)(k0 + kr) * D_S + n0 + c];
    }
    __syncthreads();
    const size_t PS = (size_t)K * D_S;
#pragma unroll
    for (int j = 0; j < 16; ++j) {
        const int nr = rq * 16 + j;
        const float xs = t[c][nr] * 32768.0f;        // exact (pow2 scale)
        const _Float16 h = (_Float16)xs;
        const float    r = xs - (float)h;            // exact
        const size_t o = (size_t)(n0 + nr) * K + k0 + c;
        Wt[o]      = h;
        Wt[o + PS] = (_Float16)(r * 2048.0f);
    }
}

// ---------------------------------------------------------------------------
// transform_mfma_all: BOTH transforms in one 768-block launch (round-8
// structure) converted to BK=32 (round-9): LDS 32 KB total -> 3 blocks/CU
// (VGPR-capped ~88+64acc), vs round-8's 64 KB/2 blocks — one more co-resident
// context to hide the per-step barrier drain (m97-ladder evidence: BK=32 at
// 3 blocks/CU is the 874-912 TF structure; BK=64-dbuf trades occupancy for
// barrier amortization at a net loss).
//
// BK=32 swizzle: 64B rows = 4x 16B blocks; stored block b of row r holds
// global k-block b ^ ((r>>1)&3) (involution; pre-swizzled global source,
// linear LDS dest, same XOR on read). 16 consecutive rows -> granule
// (4r + lg^((r>>1)&3)) mod 8 covers all 8 granules, 2-way alias = free.
//
// Numerics unchanged (scaled fp16x3, single accumulator):
// pp0 = W0*(2^11*A0), pp1 = W0*A1, pp2 = W1*A0, all at scale 2^26;
// t = 2^-26*acc + bias.
// ---------------------------------------------------------------------------
__global__ __launch_bounds__(256)
void transform_mfma_all(const _Float16* __restrict__ actS,
                        const _Float16* __restrict__ wtS,
                        const float* __restrict__ bS,
                        float* __restrict__ CS, unsigned short* __restrict__ HS,
                        const _Float16* __restrict__ actC,
                        const _Float16* __restrict__ wtC,
                        const float* __restrict__ bC,
                        float* __restrict__ CC, unsigned short* __restrict__ HC) {
    __shared__ __align__(16) _Float16 sA[2][128 * 32];  // Wt tile (8KB each)
    __shared__ __align__(16) _Float16 sB[2][128 * 32];  // Act tile
    const int tid  = threadIdx.x;
    const int lane = tid & 63;
    const int w    = tid >> 6;
    const int lr   = lane & 15, lg = lane >> 4;
    const int wn   = w & 1, wc = w >> 1;

    // per-segment XCD-chunked bijective swizzle (512%8==0, 256%8==0)
    const int hw = blockIdx.x;
    int lgid, seg;
    if (hw < 512) { seg = 0; lgid = (hw & 7) * 64 + (hw >> 3); }
    else          { const int h2 = hw - 512; seg = 1; lgid = (h2 & 7) * 32 + (h2 >> 3); }

    const _Float16* __restrict__ actP = seg ? actC : actS;
    const _Float16* __restrict__ wtP  = seg ? wtC  : wtS;
    const float* __restrict__ bias    = seg ? bC   : bS;
    float* __restrict__ C             = seg ? CC   : CS;
    unsigned short* __restrict__ H    = seg ? HC   : HS;
    const int K   = seg ? D_C : D_S;
    const int KC  = seg ? (D_C / 32) : (D_S / 32);    // 24 : 32
    const size_t aps = seg ? (size_t)B_C * D_C : (size_t)N_SRT * D_S;
    const size_t wps = (size_t)D_S * K;

    const int bn = (lgid & 7) * 128;      // out-col tile
    const int bm = (lgid >> 3) * 128;     // act-row tile

    const f32x4 vzero = {0.f, 0.f, 0.f, 0.f};
    f32x4 acc[4][4];
#pragma unroll
    for (int i = 0; i < 4; ++i)
#pragma unroll
        for (int j = 0; j < 4; ++j) acc[i][j] = vzero;

    const int NT = 3 * KC;

    auto stage = [&](int buf, int t) {
        const int pp = (t >= KC) + (t >= 2 * KC);    // 0,1,2
        const int kb = (t - pp * KC) * 32;
        const _Float16* gA = wtP  + (pp == 2 ? wps : 0) + (size_t)bn * K + kb;
        const _Float16* gB = actP + (pp == 1 ? aps : 0) + (size_t)bm * K + kb;
#pragma unroll
        for (int i = 0; i < 2; ++i) {
            const int idx = tid + i * 256;           // 0..511
            const int r   = idx >> 2;                // row 0..127
            const int sw  = ((idx & 3) ^ ((r >> 1) & 3)) * 8;  // elem offset
            GLOAD_LDS16(gA + (size_t)r * K + kb * 0 + sw,
                        (char*)&sA[buf][0] + idx * 16);
            GLOAD_LDS16(gB + (size_t)r * K + sw,
                        (char*)&sB[buf][0] + idx * 16);
        }
    };

    stage(0, 0);
    __syncthreads();

    for (int t = 0; t < NT; ++t) {
        const int cur = t & 1;
        if (t + 1 < NT) stage(cur ^ 1, t + 1);
        const bool first = (t < KC);     // pp0: scale act frags by 2^11

        half8 a[4], b[4];
#pragma unroll
        for (int t4 = 0; t4 < 4; ++t4) {
            const int ra = wn * 64 + t4 * 16 + lr;
            a[t4] = *(const half8*)((const char*)&sA[cur][0] + ra * 64 +
                                    ((lg ^ ((ra >> 1) & 3)) * 16));
            const int rb = wc * 64 + t4 * 16 + lr;
            b[t4] = *(const half8*)((const char*)&sB[cur][0] + rb * 64 +
                                    ((lg ^ ((rb >> 1) & 3)) * 16));
        }
        if (first) {
#pragma unroll
            for (int t4 = 0; t4 < 4; ++t4)
                b[t4] = b[t4] * (_Float16)2048.0f;   // exact pow2
        }
#pragma unroll
        for (int i = 0; i < 4; ++i)
#pragma unroll
            for (int j = 0; j < 4; ++j)
                acc[i][j] = __builtin_amdgcn_mfma_f32_16x16x32_f16(
                    a[i], b[j], acc[i][j], 0, 0, 0);
        __syncthreads();
    }

    // epilogue: n = bn + wn*64 + i*16 + lg*4 + q;  m = bm + wc*64 + j*16 + lr
    const float s2 = 1.4901161193847656e-8f;    // 2^-26
#pragma unroll
    for (int i = 0; i < 4; ++i) {
        const int n = bn + wn * 64 + i * 16 + lg * 4;
        const f32x4 bb = *reinterpret_cast<const f32x4*>(&bias[n]);
#pragma unroll
        for (int j = 0; j < 4; ++j) {
            const int m = bm + wc * 64 + j * 16 + lr;
            f32x4 o;
#pragma unroll
            for (int q = 0; q < 4; ++q)
                o[q] = fmaxf(fmaf(acc[i][j][q], s2, bb[q]), 0.f);
            *reinterpret_cast<f32x4*>(&C[(size_t)m * D_S + n]) = o;
            ushort4 hh;
            hh.x = f2bf(o[0]); hh.y = f2bf(o[1]);
            hh.z = f2bf(o[2]); hh.w = f2bf(o[3]);
            *reinterpret_cast<ushort4*>(&H[(size_t)m * D_S + n]) = hh;
        }
    }
}

// ---------------------------------------------------------------------------
// FALLBACK (round-5 verified): fused fp32 VALU transforms (ws too small).
// ---------------------------------------------------------------------------
#define NB0 ((B_C / 128) * (D_S / 128))     // 256
#define NB1 ((N_SRT / 128) * (D_S / 128))   // 512

__global__ __launch_bounds__(256)
void transform_fused(const float* __restrict__ A0, const float* __restrict__ W0,
                     const float* __restrict__ b0, float* __restrict__ C0,
                     unsigned short* __restrict__ H0,
                     const float* __restrict__ A1, const float* __restrict__ W1,
                     const float* __restrict__ b1, float* __restrict__ C1,
                     unsigned short* __restrict__ H1) {
    __shared__ __align__(16) float As[2][128][16];
    __shared__ __align__(16) float Bs[2][2048];

    const bool p1 = (int)blockIdx.x >= NB0;
    const int  b  = p1 ? (int)blockIdx.x - NB0 : (int)blockIdx.x;
    const float* __restrict__ A = p1 ? A1 : A0;
    const float* __restrict__ W = p1 ? W1 : W0;
    const float* __restrict__ bias = p1 ? b1 : b0;
    float* __restrict__ C = p1 ? C1 : C0;
    unsigned short* __restrict__ H = p1 ? H1 : H0;
    const int K = p1 ? D_S : D_C;

    const int bn = (b & 7) * 128;
    const int bm = (b >> 3) * 128;

    const int tid = threadIdx.x;
    const int tx = tid & 15, ty = tid >> 4;

    int a_off[2], w_off[2];
#pragma unroll
    for (int i = 0; i < 2; ++i) {
        const int idx = tid + i * 256;
        const int r = idx >> 2, q = idx & 3;
        a_off[i] = r * K + (q ^ ((r >> 3) & 3)) * 4;
        const int s = idx & 63;
        const int kloc = 2 * (idx >> 6) + ((s >> 4) & 1);
        const int cb   = 2 * (s & 15) + (s >> 5);
        w_off[i] = kloc * D_S + cb * 4;
    }

#define STAGE(bufi, k0)                                                        \
    {                                                                          \
        _Pragma("unroll")                                                      \
        for (int i = 0; i < 2; ++i) {                                          \
            const int idx = tid + i * 256;                                     \
            GLOAD_LDS16(A + (size_t)bm * K + (k0) + a_off[i],                  \
                        (char*)&As[bufi][0][0] + idx * 16);                    \
            GLOAD_LDS16(W + (size_t)(k0) * D_S + bn + w_off[i],                \
                        (char*)&Bs[bufi][0] + idx * 16);                       \
        }                                                                      \
    }

    float acc[8][8] = {};

    STAGE(0, 0);
    __syncthreads();

    const int nk = K / 16;
    for (int t = 0; t < nk; ++t) {
        const int cur = t & 1;
        if (t + 1 < nk) STAGE(t & 1 ? 0 : 1, (t + 1) * 16);

        const float* __restrict__ Bf = &Bs[cur][0];
#pragma unroll
        for (int kq = 0; kq < 4; ++kq) {
            f32x4 a4[8];
#pragma unroll
            for (int i = 0; i < 8; ++i)
                a4[i] = *reinterpret_cast<const f32x4*>(
                    &As[cur][ty * 8 + i][(kq ^ (ty & 3)) * 4]);
#pragma unroll
            for (int k2 = 0; k2 < 4; ++k2) {
                const int k = kq * 4 + k2;
                const int boff = (k >> 1) * 256 + (tx + ((k & 1) << 4)) * 4;
                const f32x4 bx = *reinterpret_cast<const f32x4*>(Bf + boff);
                const f32x4 by = *reinterpret_cast<const f32x4*>(Bf + boff + 128);
                const float bv[8] = {bx[0], bx[1], bx[2], bx[3], by[0], by[1], by[2], by[3]};
#pragma unroll
                for (int i = 0; i < 8; ++i) {
                    const float av = a4[i][k2];
#pragma unroll
                    for (int j = 0; j < 8; ++j)
                        acc[i][j] = fmaf(av, bv[j], acc[i][j]);
                }
            }
        }
        __syncthreads();
    }
#undef STAGE

    const f32x4 g0 = *reinterpret_cast<const f32x4*>(&bias[bn + tx * 8]);
    const f32x4 g1 = *reinterpret_cast<const f32x4*>(&bias[bn + tx * 8 + 4]);
#pragma unroll
    for (int i = 0; i < 8; ++i) {
        const int m = bm + ty * 8 + i;
        const int n = bn + tx * 8;
        f32x4 o0, o1;
#pragma unroll
        for (int j = 0; j < 4; ++j) {
            o0[j] = fmaxf(acc[i][j]     + g0[j], 0.f);
            o1[j] = fmaxf(acc[i][j + 4] + g1[j], 0.f);
        }
        *reinterpret_cast<f32x4*>(&C[(size_t)m * D_S + n])     = o0;
        *reinterpret_cast<f32x4*>(&C[(size_t)m * D_S + n + 4]) = o1;
        short8 h;
#pragma unroll
        for (int j = 0; j < 4; ++j) {
            h[j]     = (short)f2bf(o0[j]);
            h[j + 4] = (short)f2bf(o1[j]);
        }
        *reinterpret_cast<short8*>(&H[(size_t)m * D_S + n]) = h;
    }
}

// ---------------------------------------------------------------------------
// Kernel 2: bf16 MFMA score filter, BK=32 (round-9): LDS 32 KB -> 4 blocks/CU
// (VGPR ~52+64acc -> 4 waves/SIMD). Same stage-ahead dbuf + BK=32 swizzle as
// transform_mfma_all. Emits per-(comment, 4-group) max into G (bf16).
// ---------------------------------------------------------------------------
__global__ __launch_bounds__(256)
void scores_filter(const unsigned short* __restrict__ TSh,
                   const unsigned short* __restrict__ TCh,
                   unsigned short* __restrict__ G) {
    __shared__ __align__(16) unsigned short sA[2][128 * 32];
    __shared__ __align__(16) unsigned short sB[2][128 * 32];
    const int tid  = threadIdx.x;
    const int lane = tid & 63;
    const int w    = tid >> 6;
    const int lr   = lane & 15, lg = lane >> 4;
    const int wn   = w & 1, wc = w >> 1;
    const int n0   = blockIdx.x * 128;
    const int c0   = blockIdx.y * 128;

    const f32x4 vzero = {0.f, 0.f, 0.f, 0.f};
    f32x4 acc[4][4];
#pragma unroll
    for (int i = 0; i < 4; ++i)
#pragma unroll
        for (int j = 0; j < 4; ++j) acc[i][j] = vzero;

#define FSTAGE(bufi, kb)                                                       \
    {                                                                          \
        _Pragma("unroll")                                                      \
        for (int i = 0; i < 2; ++i) {                                          \
            const int idx = tid + i * 256;                                     \
            const int r   = idx >> 2;                                          \
            const int sw  = ((idx & 3) ^ ((r >> 1) & 3)) * 8;                  \
            GLOAD_LDS16(TSh + (size_t)(n0 + r) * D_S + (kb) + sw,              \
                        (char*)&sA[bufi][0] + idx * 16);                       \
            GLOAD_LDS16(TCh + (size_t)(c0 + r) * D_S + (kb) + sw,              \
                        (char*)&sB[bufi][0] + idx * 16);                       \
        }                                                                      \
    }

    FSTAGE(0, 0);
    __syncthreads();

    for (int kc = 0; kc < 32; ++kc) {
        const int cur = kc & 1;
        if (kc + 1 < 32) FSTAGE(cur ^ 1, (kc + 1) * 32);

        short8 a[4], b[4];
#pragma unroll
        for (int t = 0; t < 4; ++t) {
            const int ra = wn * 64 + t * 16 + lr;
            a[t] = *(const short8*)((const char*)&sA[cur][0] + ra * 64 +
                                    ((lg ^ ((ra >> 1) & 3)) * 16));
            const int rb = wc * 64 + t * 16 + lr;
            b[t] = *(const short8*)((const char*)&sB[cur][0] + rb * 64 +
                                    ((lg ^ ((rb >> 1) & 3)) * 16));
        }
#pragma unroll
        for (int i = 0; i < 4; ++i)
#pragma unroll
            for (int j = 0; j < 4; ++j)
                acc[i][j] = __builtin_amdgcn_mfma_f32_16x16x32_bf16(
                    a[i], b[j], acc[i][j], 0, 0, 0);
        __syncthreads();
    }
#undef FSTAGE

    // extraction: per-lane j-run is 4 consecutive n => natural 4-wide group max
#pragma unroll
    for (int nt = 0; nt < 4; ++nt) {
        const int n4 = (n0 >> 2) + wn * 16 + nt * 4 + lg;
#pragma unroll
        for (int ct = 0; ct < 4; ++ct) {
            const int c = c0 + wc * 64 + ct * 16 + lr;
            const f32x4 v = acc[nt][ct];
            const float m = fmaxf(fmaxf(v.x, v.y), fmaxf(v.z, v.w));
            G[(size_t)c * NGRP + n4] = f2bf(m);
        }
    }
}

// ---------------------------------------------------------------------------
// Kernel 3: per comment row, top-8 groups by approx group-max (unchanged).
// ---------------------------------------------------------------------------
__global__ __launch_bounds__(256)
void top_groups(const unsigned short* __restrict__ G, int* __restrict__ g8) {
    const int w = threadIdx.x >> 6, lane = threadIdx.x & 63;
    const int row = blockIdx.x * 4 + w;
    float v[32];
    const unsigned short* gp = G + (size_t)row * NGRP + lane * 32;
#pragma unroll
    for (int i = 0; i < 4; ++i) {
        short8 h = *(const short8*)(gp + i * 8);
#pragma unroll
        for (int j = 0; j < 8; ++j) v[i * 8 + j] = bf2f((unsigned short)h[j]);
    }
    float pv = INFINITY; int pi = -1;
    int gl[8];
#pragma unroll
    for (int k = 0; k < 8; ++k) {
        float bv = -INFINITY; int bi = NGRP;
#pragma unroll
        for (int i = 0; i < 32; ++i) {
            const int idx = lane * 32 + i;
            const bool after  = (v[i] < pv) || (v[i] == pv && idx > pi);
            const bool before = (v[i] > bv) || (v[i] == bv && idx < bi);
            if (after && before) { bv = v[i]; bi = idx; }
        }
#pragma unroll
        for (int off = 32; off >= 1; off >>= 1) {
            const float ov = __shfl_xor(bv, off);
            const int   oi = __shfl_xor(bi, off);
            if ((ov > bv) || (ov == bv && oi < bi)) { bv = ov; bi = oi; }
        }
        gl[k] = bi; pv = bv; pi = bi;
    }
#pragma unroll
    for (int a = 0; a < 8; ++a)
#pragma unroll
        for (int b2 = 0; b2 < 7; ++b2)
            if (gl[b2] > gl[b2 + 1]) { int t = gl[b2]; gl[b2] = gl[b2 + 1]; gl[b2 + 1] = t; }
    if (lane == 0) {
        int4 lo = make_int4(gl[0], gl[1], gl[2], gl[3]);
        int4 hi = make_int4(gl[4], gl[5], gl[6], gl[7]);
        *reinterpret_cast<int4*>(g8 + (size_t)row * 8)     = lo;
        *reinterpret_cast<int4*>(g8 + (size_t)row * 8 + 4) = hi;
    }
}

// ---------------------------------------------------------------------------
// Kernel 4: exact fp32 refine of the 32 candidates per row (unchanged).
// ---------------------------------------------------------------------------
__global__ __launch_bounds__(256)
void refine(const float* __restrict__ t_c, const float* __restrict__ t_s,
            const int* __restrict__ g8, int* __restrict__ tidx) {
    __shared__ float tc[D_S];
    __shared__ float sc[4 * PGRP];
    const int row = blockIdx.x;
    const int tid = threadIdx.x;
    *reinterpret_cast<float4*>(&tc[tid * 4]) =
        *reinterpret_cast<const float4*>(&t_c[(size_t)row * D_S + tid * 4]);
    __syncthreads();
    const int w = tid >> 6, lane = tid & 63;
    float4 c4[4];
#pragma unroll
    for (int q = 0; q < 4; ++q)
        c4[q] = *reinterpret_cast<const float4*>(&tc[lane * 16 + q * 4]);
#pragma unroll
    for (int i = 0; i < 2; ++i) {
        const int slotg = w * 2 + i;
        const int g = g8[(size_t)row * 8 + slotg];
#pragma unroll
        for (int o = 0; o < 4; ++o) {
            const int n = g * 4 + o;
            const float* ts = t_s + (size_t)n * D_S + lane * 16;
            float p = 0.f;
#pragma unroll
            for (int q = 0; q < 4; ++q) {
                const float4 tv = *reinterpret_cast<const float4*>(ts + q * 4);
                p += c4[q].x * tv.x + c4[q].y * tv.y + c4[q].z * tv.z + c4[q].w * tv.w;
            }
#pragma unroll
            for (int off = 32; off >= 1; off >>= 1) p += __shfl_xor(p, off);
            if (lane == 0) sc[slotg * 4 + o] = p;
        }
    }
    __syncthreads();
    if (tid == 0) {
        float v1 = -INFINITY, v2 = -INFINITY; int i1 = 0, i2 = 0;
#pragma unroll
        for (int s = 0; s < 4 * PGRP; ++s) {
            const int n = g8[(size_t)row * 8 + (s >> 2)] * 4 + (s & 3);
            const float v = sc[s];
            if (v > v1)      { v2 = v1; i2 = i1; v1 = v; i1 = n; }
            else if (v > v2) { v2 = v; i2 = n; }
        }
        tidx[row * 2 + 0] = i1;
        tidx[row * 2 + 1] = i2;
    }
}

// ---------------------------------------------------------------------------
// Kernel 5: gather selected transformed-srt rows (unchanged).
// ---------------------------------------------------------------------------
__global__ __launch_bounds__(256)
void gather_rows(const float* __restrict__ TS, const int* __restrict__ topIdx,
                 float* __restrict__ out) {
    const int row = blockIdx.x;
    const int src = topIdx[row];
    const int tid = threadIdx.x;
    const float4 v = *reinterpret_cast<const float4*>(&TS[(size_t)src * D_S + tid * 4]);
    *reinterpret_cast<float4*>(&out[(size_t)row * D_S + tid * 4]) = v;
}

// ---------------------------------------------------------------------------
extern "C" void kernel_launch(void* const* d_in, const int* in_sizes, int n_in,
                              void* d_out, int out_size, void* d_ws, size_t ws_size,
                              hipStream_t stream) {
    const float* srt      = (const float*)d_in[0];  // [8192,1024]
    const float* comments = (const float*)d_in[1];  // [4096,768]
    const float* Wc       = (const float*)d_in[2];  // [768,1024]
    const float* bc       = (const float*)d_in[3];  // [1024]
    const float* Ws       = (const float*)d_in[4];  // [1024,1024]
    const float* bs       = (const float*)d_in[5];  // [1024]
    float* out = (float*)d_out;

    // base workspace layout (identical to previous rounds)
    char* p = (char*)d_ws;
    float* t_c = (float*)p;          p += (size_t)B_C * D_S * 4;     // 16 MB
    float* t_s = (float*)p;          p += (size_t)N_SRT * D_S * 4;   // 32 MB
    unsigned short* tc_h = (unsigned short*)p; p += (size_t)B_C * D_S * 2;    // 8 MB
    unsigned short* ts_h = (unsigned short*)p; p += (size_t)N_SRT * D_S * 2;  // 16 MB
    unsigned short* G    = (unsigned short*)p; p += (size_t)B_C * NGRP * 2;   // 16 MB
    int* g8   = (int*)p;             p += (size_t)B_C * PGRP * 4;
    int* tidx = (int*)p;             p += (size_t)B_C * KSEL * 4;

    // fp16 2-plane workspace (appended; ~53.4 MB)
    _Float16* actS = (_Float16*)p; p += 2 * (size_t)N_SRT * D_S * 2; // 33.5 MB
    _Float16* actC = (_Float16*)p; p += 2 * (size_t)B_C * D_C * 2;   // 12.6 MB
    _Float16* wtS  = (_Float16*)p; p += 2 * (size_t)D_S * D_S * 2;   // 4.2 MB
    _Float16* wtC  = (_Float16*)p; p += 2 * (size_t)D_S * D_C * 2;   // 3.1 MB
    const size_t required = (size_t)(p - (char*)d_ws);

    if (ws_size >= required) {
        // --- scaled fp16x3 MFMA transform path (single fused launch) ---
        split_act<<<(N_SRT * D_S / 8 + B_C * D_C / 8) / 256, 256, 0, stream>>>(
            srt, comments, actS, actC);
        split_w<<<dim3(D_S / 64, D_S / 64), 256, 0, stream>>>(Ws, wtS, D_S);
        split_w<<<dim3(D_S / 64, D_C / 64), 256, 0, stream>>>(Wc, wtC, D_C);

        transform_mfma_all<<<512 + 256, 256, 0, stream>>>(
            actS, wtS, bs, t_s, ts_h,
            actC, wtC, bc, t_c, tc_h);
    } else {
        // --- fallback: round-5 verified fp32 VALU path ---
        transform_fused<<<NB0 + NB1, 256, 0, stream>>>(
            comments, Wc, bc, t_c, tc_h,
            srt,      Ws, bs, t_s, ts_h);
    }

    scores_filter<<<dim3(N_SRT / 128, B_C / 128), 256, 0, stream>>>(ts_h, tc_h, G);
    top_groups<<<B_C / 4, 256, 0, stream>>>(G, g8);
    refine<<<B_C, 256, 0, stream>>>(t_c, t_s, g8, tidx);
    gather_rows<<<B_C * KSEL, 256, 0, stream>>>(t_s, tidx, out);
}